// Round 29
// baseline (1240.414 us; speedup 1.0000x reference)
//
#include <hip/hip_runtime.h>
#include <math.h>

#define L 2304
#define NB 4
#define NCH 36
#define STILE 64
#define SPAD 68
#define DLU_PAD 130   // 2*STILE + 2

typedef __attribute__((ext_vector_type(8))) short short8v;
typedef __attribute__((ext_vector_type(4))) float f32x4;

__device__ inline unsigned short f2bf(float x) {
    unsigned u = __float_as_uint(x);
    return (unsigned short)((u + 0x7fffu + ((u >> 16) & 1u)) >> 16);
}
__device__ inline void split1(float x, unsigned short& h, unsigned short& l) {
    h = f2bf(x);
    float hf = __uint_as_float((unsigned)h << 16);
    l = f2bf(x - hf);
}

// async global->LDS 16B copy (linear dest = wave-uniform base + lane*16)
__device__ __forceinline__ void gload16(const unsigned short* g, unsigned short* l)
{
    __builtin_amdgcn_global_load_lds(
        (const __attribute__((address_space(1))) unsigned int*)g,
        (__attribute__((address_space(3))) unsigned int*)l, 16, 0, 0);
}

// 16-lane sum-reduce on the VALU pipe via DPP (no DS ops).
__device__ inline float row_reduce16(float v) {
    v += __int_as_float(__builtin_amdgcn_update_dpp(0, __float_as_int(v), 0xB1, 0xF, 0xF, true));
    v += __int_as_float(__builtin_amdgcn_update_dpp(0, __float_as_int(v), 0x4E, 0xF, 0xF, true));
    v += __int_as_float(__builtin_amdgcn_update_dpp(0, __float_as_int(v), 0x124, 0xF, 0xF, true));
    v += __int_as_float(__builtin_amdgcn_update_dpp(0, __float_as_int(v), 0x128, 0xF, 0xF, true));
    return v;
}

// ---------------------------------------------------------------------------
// f32 -> (hi,lo) bf16 split, layout-preserving. n multiple of 1024.
// ---------------------------------------------------------------------------
__global__ __launch_bounds__(256) void split_kernel(
    const float* __restrict__ src, unsigned short* __restrict__ hi,
    unsigned short* __restrict__ lo, int n)
{
    int i = (blockIdx.x * 256 + threadIdx.x) * 4;
    if (i >= n) return;
    float4 v = *(const float4*)(src + i);
    unsigned short h0, h1, h2, h3, l0, l1, l2, l3;
    split1(v.x, h0, l0); split1(v.y, h1, l1);
    split1(v.z, h2, l2); split1(v.w, h3, l3);
    ushort4 hv; hv.x = h0; hv.y = h1; hv.z = h2; hv.w = h3;
    ushort4 lv; lv.x = l0; lv.y = l1; lv.z = l2; lv.w = l3;
    *(ushort4*)(hi + i) = hv;
    *(ushort4*)(lo + i) = lv;
}

// ---------------------------------------------------------------------------
// Transposing split: src[C][L] f32 -> hiT/loT[L][C] bf16. (fallback path use)
// ---------------------------------------------------------------------------
__global__ __launch_bounds__(256) void split_t_kernel(
    const float* __restrict__ src, unsigned short* __restrict__ hiT,
    unsigned short* __restrict__ loT, int C)
{
    __shared__ float tile[64][65];
    const int l0 = blockIdx.x * 64, c0 = blockIdx.y * 64;
    const int li = threadIdx.x & 63, q = threadIdx.x >> 6;
    for (int cc = q; cc < 64; cc += 4)
        tile[cc][li] = src[(long)(c0 + cc) * L + l0 + li];
    __syncthreads();
    const int ci = threadIdx.x & 63;
    for (int ll = q; ll < 64; ll += 4) {
        float x = tile[ci][ll];
        unsigned short h, l;
        split1(x, h, l);
        long o = (long)(l0 + ll) * C + c0 + ci;
        hiT[o] = h;
        loT[o] = l;
    }
}

// ---------------------------------------------------------------------------
// Split-bf16 MFMA GEMM, 128x128 tile: C[m,n] = sum_k A[m,k]*B^T[n,k].
// gload_lds staging with XOR swizzle; natural block mapping (gridDim.x%8==0).
// ---------------------------------------------------------------------------
__global__ __launch_bounds__(256) void gemm_mfma(
    const unsigned short* __restrict__ Ahi, const unsigned short* __restrict__ Alo, int lda,
    const unsigned short* __restrict__ Bhi, const unsigned short* __restrict__ Blo, int ldb,
    float* __restrict__ C, long cms, long cns, int K, int act,
    const float* __restrict__ emu, const float* __restrict__ ers,
    const float* __restrict__ es1, const float* __restrict__ es2)
{
    __shared__ unsigned short Ah[128 * 32], Al[128 * 32], Bh[128 * 32], Bl[128 * 32];
    const int tid = threadIdx.x;
    const int lane = tid & 63, wave = tid >> 6;
    const int wm = (wave >> 1) * 64, wn = (wave & 1) * 64;
    const int m0 = blockIdx.x * 128, n0 = blockIdx.y * 128;
    const int rowS = tid >> 2;
    const int cS = ((tid & 3) ^ ((tid >> 3) & 3)) * 8;
    const unsigned short* gAh0 = Ahi + (long)(m0 + rowS) * lda + cS;
    const unsigned short* gAl0 = Alo + (long)(m0 + rowS) * lda + cS;
    const unsigned short* gBh0 = Bhi + (long)(n0 + rowS) * ldb + cS;
    const unsigned short* gBl0 = Blo + (long)(n0 + rowS) * ldb + cS;
    const long a64 = (long)64 * lda, b64 = (long)64 * ldb;
    unsigned short* lAh0 = Ah + tid * 8;  unsigned short* lAh1 = Ah + 2048 + tid * 8;
    unsigned short* lAl0 = Al + tid * 8;  unsigned short* lAl1 = Al + 2048 + tid * 8;
    unsigned short* lBh0 = Bh + tid * 8;  unsigned short* lBh1 = Bh + 2048 + tid * 8;
    unsigned short* lBl0 = Bl + tid * 8;  unsigned short* lBl1 = Bl + 2048 + tid * 8;
    const int fr = lane & 15;
    const int chq = (((lane >> 4) ^ ((fr >> 1) & 3)) << 3);

    f32x4 acc[4][4];
#pragma unroll
    for (int i = 0; i < 4; ++i)
#pragma unroll
        for (int j = 0; j < 4; ++j) acc[i][j] = (f32x4){0.f, 0.f, 0.f, 0.f};

    for (int k0 = 0; k0 < K; k0 += 32) {
        gload16(gAh0 + k0, lAh0); gload16(gAh0 + a64 + k0, lAh1);
        gload16(gAl0 + k0, lAl0); gload16(gAl0 + a64 + k0, lAl1);
        gload16(gBh0 + k0, lBh0); gload16(gBh0 + b64 + k0, lBh1);
        gload16(gBl0 + k0, lBl0); gload16(gBl0 + b64 + k0, lBl1);
        __syncthreads();
        short8v bhf[4], blf[4];
#pragma unroll
        for (int nf = 0; nf < 4; ++nf) {
            bhf[nf] = *(const short8v*)&Bh[(wn + nf * 16 + fr) * 32 + chq];
            blf[nf] = *(const short8v*)&Bl[(wn + nf * 16 + fr) * 32 + chq];
        }
#pragma unroll
        for (int mf = 0; mf < 4; ++mf) {
            short8v ah = *(const short8v*)&Ah[(wm + mf * 16 + fr) * 32 + chq];
            short8v al = *(const short8v*)&Al[(wm + mf * 16 + fr) * 32 + chq];
#pragma unroll
            for (int nf = 0; nf < 4; ++nf) {
                acc[mf][nf] = __builtin_amdgcn_mfma_f32_16x16x32_bf16(ah, bhf[nf], acc[mf][nf], 0, 0, 0);
                acc[mf][nf] = __builtin_amdgcn_mfma_f32_16x16x32_bf16(ah, blf[nf], acc[mf][nf], 0, 0, 0);
                acc[mf][nf] = __builtin_amdgcn_mfma_f32_16x16x32_bf16(al, bhf[nf], acc[mf][nf], 0, 0, 0);
            }
        }
        __syncthreads();
    }
    const int rb = (lane >> 4) * 4;
#pragma unroll
    for (int mf = 0; mf < 4; ++mf) {
#pragma unroll
        for (int nf = 0; nf < 4; ++nf) {
            int n = n0 + wn + nf * 16 + fr;
            int mb = m0 + wm + mf * 16 + rb;
            if (cms == 1) {
                float4 r;
                r.x = acc[mf][nf][0]; r.y = acc[mf][nf][1];
                r.z = acc[mf][nf][2]; r.w = acc[mf][nf][3];
                *(float4*)(C + (long)n * cns + mb) = r;
            } else {
#pragma unroll
                for (int r = 0; r < 4; ++r) {
                    int m = mb + r;
                    float v = acc[mf][nf][r];
                    if (act == 2) v = (v - emu[n] * es1[m]) * ers[n] + es2[m];
                    C[(long)m * cms + n] = v;
                }
            }
        }
    }
}

// ---------------------------------------------------------------------------
// Split-K 128x128-tile MFMA GEMM: blockIdx.z = K-slice. 48 MFMA per K-step.
// gload_lds staging + XCD-aware bijective block swizzle.
// ---------------------------------------------------------------------------
__global__ __launch_bounds__(256) void gemm_mfma128sk(
    const unsigned short* __restrict__ Ahi, const unsigned short* __restrict__ Alo, int lda,
    const unsigned short* __restrict__ Bhi, const unsigned short* __restrict__ Blo, int ldb,
    float* __restrict__ P, int KS, int Mstride)
{
    __shared__ unsigned short Ah[128 * 32], Al[128 * 32], Bh[128 * 32], Bl[128 * 32];
    const int tid = threadIdx.x;
    const int lane = tid & 63, wave = tid >> 6;
    const int wm = (wave >> 1) * 64, wn = (wave & 1) * 64;
    const int nwg = gridDim.x * gridDim.y * gridDim.z;
    const int bid = blockIdx.x + gridDim.x * (blockIdx.y + gridDim.y * blockIdx.z);
    const int cpx = nwg >> 3;
    const int swz = (bid & 7) * cpx + (bid >> 3);
    const int bx = swz % gridDim.x;
    const int rest = swz / gridDim.x;
    const int by = rest % gridDim.y;
    const int sl = rest / gridDim.y;
    const int m0 = bx * 128, n0 = by * 128;
    const int kbase = sl * KS;
    const int rowS = tid >> 2;
    const int cS = ((tid & 3) ^ ((tid >> 3) & 3)) * 8;
    const unsigned short* gAh0 = Ahi + (long)(m0 + rowS) * lda + kbase + cS;
    const unsigned short* gAl0 = Alo + (long)(m0 + rowS) * lda + kbase + cS;
    const unsigned short* gBh0 = Bhi + (long)(n0 + rowS) * ldb + kbase + cS;
    const unsigned short* gBl0 = Blo + (long)(n0 + rowS) * ldb + kbase + cS;
    const long a64 = (long)64 * lda, b64 = (long)64 * ldb;
    unsigned short* lAh0 = Ah + tid * 8;  unsigned short* lAh1 = Ah + 2048 + tid * 8;
    unsigned short* lAl0 = Al + tid * 8;  unsigned short* lAl1 = Al + 2048 + tid * 8;
    unsigned short* lBh0 = Bh + tid * 8;  unsigned short* lBh1 = Bh + 2048 + tid * 8;
    unsigned short* lBl0 = Bl + tid * 8;  unsigned short* lBl1 = Bl + 2048 + tid * 8;
    const int fr = lane & 15;
    const int chq = (((lane >> 4) ^ ((fr >> 1) & 3)) << 3);

    f32x4 acc[4][4];
#pragma unroll
    for (int i = 0; i < 4; ++i)
#pragma unroll
        for (int j = 0; j < 4; ++j) acc[i][j] = (f32x4){0.f, 0.f, 0.f, 0.f};

    for (int k0 = 0; k0 < KS; k0 += 32) {
        gload16(gAh0 + k0, lAh0); gload16(gAh0 + a64 + k0, lAh1);
        gload16(gAl0 + k0, lAl0); gload16(gAl0 + a64 + k0, lAl1);
        gload16(gBh0 + k0, lBh0); gload16(gBh0 + b64 + k0, lBh1);
        gload16(gBl0 + k0, lBl0); gload16(gBl0 + b64 + k0, lBl1);
        __syncthreads();
        short8v bhf[4], blf[4];
#pragma unroll
        for (int nf = 0; nf < 4; ++nf) {
            bhf[nf] = *(const short8v*)&Bh[(wn + nf * 16 + fr) * 32 + chq];
            blf[nf] = *(const short8v*)&Bl[(wn + nf * 16 + fr) * 32 + chq];
        }
#pragma unroll
        for (int mf = 0; mf < 4; ++mf) {
            short8v ah = *(const short8v*)&Ah[(wm + mf * 16 + fr) * 32 + chq];
            short8v al = *(const short8v*)&Al[(wm + mf * 16 + fr) * 32 + chq];
#pragma unroll
            for (int nf = 0; nf < 4; ++nf) {
                acc[mf][nf] = __builtin_amdgcn_mfma_f32_16x16x32_bf16(ah, bhf[nf], acc[mf][nf], 0, 0, 0);
                acc[mf][nf] = __builtin_amdgcn_mfma_f32_16x16x32_bf16(ah, blf[nf], acc[mf][nf], 0, 0, 0);
                acc[mf][nf] = __builtin_amdgcn_mfma_f32_16x16x32_bf16(al, bhf[nf], acc[mf][nf], 0, 0, 0);
            }
        }
        __syncthreads();
    }
    const int rb = (lane >> 4) * 4;
    float* Pp = P + (long)sl * Mstride * L;
#pragma unroll
    for (int mf = 0; mf < 4; ++mf) {
#pragma unroll
        for (int nf = 0; nf < 4; ++nf) {
            int n = n0 + wn + nf * 16 + fr;
            int mb = m0 + wm + mf * 16 + rb;
            float4 r;
            r.x = acc[mf][nf][0]; r.y = acc[mf][nf][1];
            r.z = acc[mf][nf][2]; r.w = acc[mf][nf][3];
            *(float4*)(Pp + (long)n * Mstride + mb) = r;
        }
    }
}

// out_proj reduce: sum 8 slices of P[sl][n][512]
__global__ __launch_bounds__(256) void out_reduce(
    const float* __restrict__ P, float* __restrict__ out)
{
    const long E = (long)512 * L;
    long i = ((long)blockIdx.x * 256 + threadIdx.x) * 4;
    float4 r = *(const float4*)(P + i);
#pragma unroll
    for (int s = 1; s < 8; ++s) {
        float4 a = *(const float4*)(P + (long)s * E + i);
        r.x += a.x; r.y += a.y; r.z += a.z; r.w += a.w;
    }
    *(float4*)(out + i) = r;
}

// ---------------------------------------------------------------------------
// Fuse split-K reduce -> direct bf16-split transposed B write.
// P[sl][l][1024] (already l-major); sum 4 slices, LN-affine epilogue,
// split1, write BT[l][3072] columns 2048..3071.
// ---------------------------------------------------------------------------
__global__ __launch_bounds__(256) void fuse_reduce_bt(
    const float* __restrict__ P,
    const float* __restrict__ emu, const float* __restrict__ ers,
    const float* __restrict__ es1, const float* __restrict__ es2,
    unsigned short* __restrict__ BT_hi, unsigned short* __restrict__ BT_lo)
{
    const long E = (long)1024 * L;
    long idx = (long)blockIdx.x * 256 + threadIdx.x;   // over L*256
    int l = (int)(idx >> 8);
    int dq = (int)(idx & 255) * 4;
    long base = (long)l * 1024 + dq;
    float4 a = *(const float4*)(P + base);
    float4 b = *(const float4*)(P + E + base);
    float4 c = *(const float4*)(P + 2 * E + base);
    float4 d = *(const float4*)(P + 3 * E + base);
    float v[4];
    v[0] = (a.x + b.x) + (c.x + d.x);
    v[1] = (a.y + b.y) + (c.y + d.y);
    v[2] = (a.z + b.z) + (c.z + d.z);
    v[3] = (a.w + b.w) + (c.w + d.w);
    float mu = emu[l], rs = ers[l];
    unsigned short hv[4], lv[4];
#pragma unroll
    for (int j = 0; j < 4; ++j) {
        int m = dq + j;
        float x = (v[j] - mu * es1[m]) * rs + es2[m];
        split1(x, hv[j], lv[j]);
    }
    long o = (long)l * 3072 + 2048 + dq;
    ushort4 h4; h4.x = hv[0]; h4.y = hv[1]; h4.z = hv[2]; h4.w = hv[3];
    ushort4 l4; l4.x = lv[0]; l4.y = lv[1]; l4.z = lv[2]; l4.w = lv[3];
    *(ushort4*)(BT_hi + o) = h4;
    *(ushort4*)(BT_lo + o) = l4;
}

// ---------------------------------------------------------------------------
// Generic f32 tiled GEMM (dt_proj and fallback).
// ---------------------------------------------------------------------------
__global__ __launch_bounds__(256) void gemm_f32(
    const float* __restrict__ A, int lda,
    const float* __restrict__ B, long ldb, int b_nk, long bbs,
    float* __restrict__ C, long cms, long cns, long cbs,
    int M, int N, int K,
    const float* __restrict__ bias, int act,
    const float* __restrict__ emu, const float* __restrict__ ers,
    const float* __restrict__ es1, const float* __restrict__ es2)
{
    __shared__ float As[16][65];
    __shared__ float Bs[16][65];
    const int tid = threadIdx.x;
    const int tx = tid & 15, ty = tid >> 4;
    const int m0 = blockIdx.x * 64, n0 = blockIdx.y * 64;
    const int bz = blockIdx.z;
    const float* Bb = B + (long)bz * bbs;
    float acc[4][4];
#pragma unroll
    for (int i = 0; i < 4; ++i)
#pragma unroll
        for (int j = 0; j < 4; ++j) acc[i][j] = 0.f;

    for (int k0 = 0; k0 < K; k0 += 16) {
        {
            int m = tid >> 2, kq = (tid & 3) << 2;
            float4 v = *(const float4*)(A + (long)(m0 + m) * lda + (k0 + kq));
            As[kq + 0][m] = v.x; As[kq + 1][m] = v.y; As[kq + 2][m] = v.z; As[kq + 3][m] = v.w;
        }
        if (b_nk) {
            int n = tid >> 2, kq = (tid & 3) << 2;
            float4 v = *(const float4*)(Bb + (long)(n0 + n) * ldb + (k0 + kq));
            Bs[kq + 0][n] = v.x; Bs[kq + 1][n] = v.y; Bs[kq + 2][n] = v.z; Bs[kq + 3][n] = v.w;
        } else {
            int k = tid >> 4, nq = (tid & 15) << 2;
            float4 v = *(const float4*)(Bb + (long)(k0 + k) * ldb + (n0 + nq));
            Bs[k][nq + 0] = v.x; Bs[k][nq + 1] = v.y; Bs[k][nq + 2] = v.z; Bs[k][nq + 3] = v.w;
        }
        __syncthreads();
#pragma unroll
        for (int kk = 0; kk < 16; ++kk) {
            float a[4], b[4];
#pragma unroll
            for (int i = 0; i < 4; ++i) a[i] = As[kk][ty * 4 + i];
#pragma unroll
            for (int j = 0; j < 4; ++j) b[j] = Bs[kk][tx * 4 + j];
#pragma unroll
            for (int i = 0; i < 4; ++i)
#pragma unroll
                for (int j = 0; j < 4; ++j) acc[i][j] = fmaf(a[i], b[j], acc[i][j]);
        }
        __syncthreads();
    }
#pragma unroll
    for (int i = 0; i < 4; ++i) {
        int m = m0 + ty * 4 + i;
        float bs = bias ? bias[m] : 0.f;
        float s1 = es1 ? es1[m] : 0.f;
        float s2 = es2 ? es2[m] : 0.f;
#pragma unroll
        for (int j = 0; j < 4; ++j) {
            int n = n0 + tx * 4 + j;
            float v = acc[i][j] + bs;
            if (act == 1) v = (v > 20.f) ? v : log1pf(expf(v));
            else if (act == 2) {
                float mu = emu[n];
                float rs = ers[n];
                v = (v - mu * s1) * rs + s2;
            }
            C[(long)bz * cbs + (long)m * cms + (long)n * cns] = v;
        }
    }
}

// ---------------------------------------------------------------------------
// x_proj split-K: partial[sl][dir][64][L] = W[64, sl*256..+256) . xconv slice
// ---------------------------------------------------------------------------
__global__ __launch_bounds__(256) void xproj_partial(
    const float* __restrict__ W, const float* __restrict__ xconv,
    float* __restrict__ P)
{
    __shared__ float As[16][65];
    __shared__ float Bs[16][65];
    const int tid = threadIdx.x;
    const int tx = tid & 15, ty = tid >> 4;
    const int n0 = blockIdx.x * 64;
    const int dir = blockIdx.y, sl = blockIdx.z;
    const float* A = W + sl * 256;                                  // lda=1024
    const float* B = xconv + ((long)dir * 1024 + sl * 256) * L;     // [256][L]
    float* Pp = P + ((long)sl * 2 + dir) * 64 * L;
    float acc[4][4];
#pragma unroll
    for (int i = 0; i < 4; ++i)
#pragma unroll
        for (int j = 0; j < 4; ++j) acc[i][j] = 0.f;

    for (int k0 = 0; k0 < 256; k0 += 16) {
        {
            int m = tid >> 2, kq = (tid & 3) << 2;
            float4 v = *(const float4*)(A + (long)m * 1024 + (k0 + kq));
            As[kq + 0][m] = v.x; As[kq + 1][m] = v.y; As[kq + 2][m] = v.z; As[kq + 3][m] = v.w;
        }
        {
            int k = tid >> 4, nq = (tid & 15) << 2;
            float4 v = *(const float4*)(B + (long)(k0 + k) * L + (n0 + nq));
            Bs[k][nq + 0] = v.x; Bs[k][nq + 1] = v.y; Bs[k][nq + 2] = v.z; Bs[k][nq + 3] = v.w;
        }
        __syncthreads();
#pragma unroll
        for (int kk = 0; kk < 16; ++kk) {
            float a[4], b[4];
#pragma unroll
            for (int i = 0; i < 4; ++i) a[i] = As[kk][ty * 4 + i];
#pragma unroll
            for (int j = 0; j < 4; ++j) b[j] = Bs[kk][tx * 4 + j];
#pragma unroll
            for (int i = 0; i < 4; ++i)
#pragma unroll
                for (int j = 0; j < 4; ++j) acc[i][j] = fmaf(a[i], b[j], acc[i][j]);
        }
        __syncthreads();
    }
#pragma unroll
    for (int i = 0; i < 4; ++i) {
        int m = ty * 4 + i;
        float4 r;
        r.x = acc[i][0]; r.y = acc[i][1]; r.z = acc[i][2]; r.w = acc[i][3];
        *(float4*)(Pp + (long)m * L + n0 + tx * 4) = r;
    }
}

__global__ __launch_bounds__(256) void xproj_reduce(
    const float* __restrict__ P, float* __restrict__ xdbl)
{
    const long E = (long)2 * 64 * L;                 // 294912
    long i = ((long)blockIdx.x * 256 + threadIdx.x) * 4;
    float4 a = *(const float4*)(P + i);
    float4 b = *(const float4*)(P + E + i);
    float4 c = *(const float4*)(P + 2 * E + i);
    float4 d = *(const float4*)(P + 3 * E + i);
    float4 r;
    r.x = (a.x + b.x) + (c.x + d.x);
    r.y = (a.y + b.y) + (c.y + d.y);
    r.z = (a.z + b.z) + (c.z + d.z);
    r.w = (a.w + b.w) + (c.w + d.w);
    *(float4*)(xdbl + i) = r;
}

// ---------------------------------------------------------------------------
// Mamba causal depthwise conv (k=4) + bias + SiLU, per batch.
// ---------------------------------------------------------------------------
__global__ __launch_bounds__(256) void mamba_conv_kernel(
    const float* __restrict__ xz_b, const float* __restrict__ w,
    const float* __restrict__ bias, float* __restrict__ xout)
{
    long idx = (long)blockIdx.x * 256 + threadIdx.x;   // over 2*1024*L
    int l = (int)(idx % L);
    long r = idx / L;
    int d = (int)(r % 1024);
    int dir = (int)(r / 1024);
    const float* src = xz_b + ((dir ? 2048 : 0) + (long)d) * L;
    float acc = bias[d];
#pragma unroll
    for (int j = 0; j < 4; ++j) {
        int t = l - 3 + j;
        if (t >= 0) {
            float v = dir ? src[L - 1 - t] : src[t];
            acc = fmaf(w[d * 4 + j], v, acc);
        }
    }
    xout[idx] = acc / (1.f + expf(-acc));  // silu
}

// ---------------------------------------------------------------------------
// Chunked selective scan. DS-minimized: interleaved float2 LDS rows
// (1 ds_read_b64 for dl/u, 1 for B/C) and DPP-based 16-lane reduction.
// ---------------------------------------------------------------------------
__global__ __launch_bounds__(256) void scan_pass1(
    const float* __restrict__ delta_b, const float* __restrict__ xconv_b,
    const float* __restrict__ xdbl_b, const float* __restrict__ A_log,
    float* __restrict__ hend, float* __restrict__ pAb)
{
    __shared__ float s_dlu[16][DLU_PAD];
    __shared__ float s_B[16][SPAD];
    const int tid = threadIdx.x;
    const int dir = blockIdx.y, ch = blockIdx.z;
    const int n = tid & 15, dloc = tid >> 4;
    const int d0 = blockIdx.x * 16;
    const int d = d0 + dloc;
    const int t0 = ch * STILE;
    const float Adn = -expf(A_log[d * 16 + n]);
    const float* dl_p = delta_b + ((long)dir * 1024 + d0) * L;
    const float* u_p  = xconv_b + ((long)dir * 1024 + d0) * L;
    const float* B_p  = xdbl_b + ((long)dir * 64 + 32) * L;
    const int lch = tid >> 4, lq = tid & 15;
    {
        float4 a = *(const float4*)(dl_p + (long)lch * L + t0 + lq * 4);
        float4 b = *(const float4*)(u_p + (long)lch * L + t0 + lq * 4);
        float4 w0; w0.x = a.x; w0.y = b.x; w0.z = a.y; w0.w = b.y;
        float4 w1; w1.x = a.z; w1.y = b.z; w1.z = a.w; w1.w = b.w;
        *(float4*)&s_dlu[lch][lq * 8] = w0;
        *(float4*)&s_dlu[lch][lq * 8 + 4] = w1;
        float4 v = *(const float4*)(B_p + (long)lch * L + t0 + lq * 4);
        *(float4*)&s_B[lch][lq * 4] = v;
    }
    __syncthreads();
    float h = 0.f, p = 1.f;
#pragma unroll 4
    for (int tt = 0; tt < STILE; ++tt) {
        float2 dlu = *(const float2*)&s_dlu[dloc][tt * 2];
        float Bv = s_B[n][tt];
        float dA = __expf(dlu.x * Adn);
        h = fmaf(dA, h, dlu.x * dlu.y * Bv);
        p *= dA;
    }
    long sidx = (((long)dir * NCH + ch) * 1024 + d) * 16 + n;
    hend[sidx] = h;
    pAb[sidx] = p;
}

__global__ __launch_bounds__(256) void scan_fix(
    const float* __restrict__ hend, const float* __restrict__ pAb,
    float* __restrict__ hin)
{
    int tid = blockIdx.x * 256 + threadIdx.x;      // 32768 = 2*1024*16
    int dir = tid >> 14;
    int rest = tid & 16383;                        // d*16+n
    float h = 0.f;
#pragma unroll
    for (int c = 0; c < NCH; ++c) {
        long idx = (((long)dir * NCH + c) << 14) + rest;
        hin[idx] = h;
        h = hend[idx] + pAb[idx] * h;
    }
}

// MFMA-path scan pass 2: writes bf16-split transposed B directly into
// BT[l][3072] columns 0..2047.
__global__ __launch_bounds__(256) void scan_pass2_bt(
    const float* __restrict__ delta_b, const float* __restrict__ xconv_b,
    const float* __restrict__ xdbl_b, const float* __restrict__ xz_b,
    const float* __restrict__ A_log, const float* __restrict__ Dvec,
    const float* __restrict__ hin,
    unsigned short* __restrict__ BT_hi, unsigned short* __restrict__ BT_lo)
{
    __shared__ float s_dlu[16][DLU_PAD];   // (dl,u) pairs; dl slot reused for y
    __shared__ float s_BC[16][DLU_PAD];    // (B,C) pairs
    const int tid = threadIdx.x;
    const int dir = blockIdx.y, ch = blockIdx.z;
    const int n = tid & 15, dloc = tid >> 4;
    const int d0 = blockIdx.x * 16;
    const int d = d0 + dloc;
    const int t0 = ch * STILE;
    const int opos0 = dir ? (L - STILE - t0) : t0;
    const float Adn = -expf(A_log[d * 16 + n]);
    const float Dd = Dvec[d];
    const float* dl_p = delta_b + ((long)dir * 1024 + d0) * L;
    const float* u_p  = xconv_b + ((long)dir * 1024 + d0) * L;
    const float* B_p  = xdbl_b + ((long)dir * 64 + 32) * L;
    const float* C_p  = xdbl_b + ((long)dir * 64 + 48) * L;
    const float* z_base = xz_b + ((dir ? 3072 : 1024) + (long)d0) * L;  // z[dloc][l]
    const int lch = tid >> 4, lq = tid & 15;
    {
        float4 a = *(const float4*)(dl_p + (long)lch * L + t0 + lq * 4);
        float4 b = *(const float4*)(u_p + (long)lch * L + t0 + lq * 4);
        float4 w0; w0.x = a.x; w0.y = b.x; w0.z = a.y; w0.w = b.y;
        float4 w1; w1.x = a.z; w1.y = b.z; w1.z = a.w; w1.w = b.w;
        *(float4*)&s_dlu[lch][lq * 8] = w0;
        *(float4*)&s_dlu[lch][lq * 8 + 4] = w1;
        float4 c = *(const float4*)(B_p + (long)lch * L + t0 + lq * 4);
        float4 e = *(const float4*)(C_p + (long)lch * L + t0 + lq * 4);
        float4 x0; x0.x = c.x; x0.y = e.x; x0.z = c.y; x0.w = e.y;
        float4 x1; x1.x = c.z; x1.y = e.z; x1.z = c.w; x1.w = e.w;
        *(float4*)&s_BC[lch][lq * 8] = x0;
        *(float4*)&s_BC[lch][lq * 8 + 4] = x1;
    }
    __syncthreads();   // s_BC rows are read cross-wave
    float h = hin[(((long)dir * NCH + ch) * 1024 + d) * 16 + n];
#pragma unroll 4
    for (int tt = 0; tt < STILE; ++tt) {
        float2 dlu = *(const float2*)&s_dlu[dloc][tt * 2];
        float2 bc = *(const float2*)&s_BC[n][tt * 2];
        float dA = __expf(dlu.x * Adn);
        h = fmaf(dA, h, dlu.x * dlu.y * bc.x);
        float y = row_reduce16(h * bc.y);
        if (n == 0) s_dlu[dloc][tt * 2] = y + Dd * dlu.y;
    }
    __syncthreads();   // store phase reads s_dlu rows cross-wave
    {
        const int p = tid >> 2;              // local output position 0..63
        const int dq = (tid & 3) * 4;        // 4 channels per thread
        const int l = opos0 + p;
        const int cbase = (dir ? 1024 : 0) + d0;
        const int yi = (dir ? 63 - p : p) * 2;
        unsigned short hv[4], lv[4];
#pragma unroll
        for (int j = 0; j < 4; ++j) {
            int dl = dq + j;
            float y = s_dlu[dl][yi];
            float z = z_base[(long)dl * L + l];
            float v = y * (z / (1.f + __expf(-z)));
            split1(v, hv[j], lv[j]);
        }
        long o = (long)l * 3072 + cbase + dq;
        ushort4 h4; h4.x = hv[0]; h4.y = hv[1]; h4.z = hv[2]; h4.w = hv[3];
        ushort4 l4; l4.x = lv[0]; l4.y = lv[1]; l4.z = lv[2]; l4.w = lv[3];
        *(ushort4*)(BT_hi + o) = h4;
        *(ushort4*)(BT_lo + o) = l4;
    }
}

// f32 scan pass 2 (fallback path only)
__global__ __launch_bounds__(256) void scan_pass2(
    const float* __restrict__ delta_b, const float* __restrict__ xconv_b,
    const float* __restrict__ xdbl_b, const float* __restrict__ xz_b,
    const float* __restrict__ A_log, const float* __restrict__ Dvec,
    const float* __restrict__ hin, float* __restrict__ out_fb)
{
    __shared__ float s_dlu[16][DLU_PAD];
    __shared__ float s_BC[16][DLU_PAD];
    const int tid = threadIdx.x;
    const int dir = blockIdx.y, ch = blockIdx.z;
    const int n = tid & 15, dloc = tid >> 4;
    const int d0 = blockIdx.x * 16;
    const int d = d0 + dloc;
    const int t0 = ch * STILE;
    const int opos0 = dir ? (L - STILE - t0) : t0;
    const float Adn = -expf(A_log[d * 16 + n]);
    const float Dd = Dvec[d];
    const float* dl_p = delta_b + ((long)dir * 1024 + d0) * L;
    const float* u_p  = xconv_b + ((long)dir * 1024 + d0) * L;
    const float* B_p  = xdbl_b + ((long)dir * 64 + 32) * L;
    const float* C_p  = xdbl_b + ((long)dir * 64 + 48) * L;
    const float* z_p  = xz_b + ((dir ? 3072 : 1024) + (long)d0) * L;
    float* o_p = out_fb + ((dir ? 1024 : 0) + (long)d0) * L;
    const int lch = tid >> 4, lq = tid & 15;
    {
        float4 a = *(const float4*)(dl_p + (long)lch * L + t0 + lq * 4);
        float4 b = *(const float4*)(u_p + (long)lch * L + t0 + lq * 4);
        float4 w0; w0.x = a.x; w0.y = b.x; w0.z = a.y; w0.w = b.y;
        float4 w1; w1.x = a.z; w1.y = b.z; w1.z = a.w; w1.w = b.w;
        *(float4*)&s_dlu[lch][lq * 8] = w0;
        *(float4*)&s_dlu[lch][lq * 8 + 4] = w1;
        float4 c = *(const float4*)(B_p + (long)lch * L + t0 + lq * 4);
        float4 e = *(const float4*)(C_p + (long)lch * L + t0 + lq * 4);
        float4 x0; x0.x = c.x; x0.y = e.x; x0.z = c.y; x0.w = e.y;
        float4 x1; x1.x = c.z; x1.y = e.z; x1.z = c.w; x1.w = e.w;
        *(float4*)&s_BC[lch][lq * 8] = x0;
        *(float4*)&s_BC[lch][lq * 8 + 4] = x1;
    }
    __syncthreads();
    float h = hin[(((long)dir * NCH + ch) * 1024 + d) * 16 + n];
#pragma unroll 4
    for (int tt = 0; tt < STILE; ++tt) {
        float2 dlu = *(const float2*)&s_dlu[dloc][tt * 2];
        float2 bc = *(const float2*)&s_BC[n][tt * 2];
        float dA = __expf(dlu.x * Adn);
        h = fmaf(dA, h, dlu.x * dlu.y * bc.x);
        float y = row_reduce16(h * bc.y);
        if (n == 0) s_dlu[dloc][tt * 2] = y + Dd * dlu.y;
    }
    {
        float* po = o_p + (long)lch * L + opos0;
        const float* pz = z_p + (long)lch * L + opos0;
        int oo = lq * 4;
        float4 zv = *(const float4*)(pz + oo);
        float y0 = s_dlu[lch][(dir ? 63 - oo : oo) * 2];
        float y1 = s_dlu[lch][(dir ? 62 - oo : oo + 1) * 2];
        float y2 = s_dlu[lch][(dir ? 61 - oo : oo + 2) * 2];
        float y3 = s_dlu[lch][(dir ? 60 - oo : oo + 3) * 2];
        float4 r;
        r.x = y0 * (zv.x / (1.f + __expf(-zv.x)));
        r.y = y1 * (zv.y / (1.f + __expf(-zv.y)));
        r.z = y2 * (zv.z / (1.f + __expf(-zv.z)));
        r.w = y3 * (zv.w / (1.f + __expf(-zv.w)));
        *(float4*)(po + oo) = r;
    }
}

// ---------------------------------------------------------------------------
// Conv-branch helpers
// ---------------------------------------------------------------------------
__global__ __launch_bounds__(256) void mean_phi_kernel(
    const float* __restrict__ xz_b, const float* __restrict__ gw,
    const float* __restrict__ gb, float* __restrict__ phi_b)
{
    int c = blockIdx.x;
    const float* src = xz_b + (4608 + (long)c) * L;
    float s = 0.f;
    for (int l = threadIdx.x; l < L; l += 256) s += src[l];
    __shared__ float red[256];
    red[threadIdx.x] = s;
    __syncthreads();
    for (int st = 128; st > 0; st >>= 1) {
        if (threadIdx.x < st) red[threadIdx.x] += red[threadIdx.x + st];
        __syncthreads();
    }
    if (threadIdx.x == 0) {
        float m = red[0] / (float)L;
        phi_b[c] = fmaxf(gw[c] * m + gb[c], 0.f);
    }
}

// original flat cat_build (fallback path)
__global__ __launch_bounds__(256) void cat_build_kernel(
    const float* __restrict__ xz_b,
    const float* __restrict__ lw, const float* __restrict__ lb,
    const float* __restrict__ pw, const float* __restrict__ pb,
    const float* __restrict__ dw, const float* __restrict__ db,
    const float* __restrict__ phi_b, float* __restrict__ cat_b)
{
    long idx = (long)blockIdx.x * 256 + threadIdx.x;   // over 2048*L
    int l = (int)(idx % L);
    int cc = (int)(idx / L);
    float val;
    if (cc < 1536) {
        int i = cc >> 9, c = cc & 511, dil = 1 << i;  // dilations 1,2,4
        const float* xa = xz_b + (4096 + (long)c) * L;
        float pwv = pw[i * 512 + c], pbv = pb[i * 512 + c];
        const float* w = dw + ((long)i * 512 + c) * 3;
        float acc = db[i * 512 + c];
#pragma unroll
        for (int k = 0; k < 3; ++k) {
            int t = l + (k - 1) * dil;
            if (t >= 0 && t < L) acc += (pwv * xa[t] + pbv) * w[k];
        }
        val = acc;
    } else {
        int c = cc & 511;
        const float* xc = xz_b + (4608 + (long)c) * L;
        float acc = lb[c];
#pragma unroll
        for (int k = 0; k < 3; ++k) {
            int t = l - 1 + k;
            if (t >= 0 && t < L) acc += xc[t] * lw[c * 3 + k];
        }
        float g = 0.5f * acc * (1.f + erff(acc * 0.70710678118f));
        val = phi_b[c] * g;
    }
    cat_b[idx] = val;
}

// ---------------------------------------------------------------------------
// cat_build + transposed bf16 split fused (MFMA path): 64x64 tiles; computes
// cat values (identical per-element arithmetic to cat_build_kernel), writes
// f32 cat_b[c][l] (for LN stats) AND BT[l][2048] hi/lo via LDS transpose
// (split_t's exact output values -> bit-identical).
// ---------------------------------------------------------------------------
__global__ __launch_bounds__(256) void cat_build_bt_kernel(
    const float* __restrict__ xz_b,
    const float* __restrict__ lw, const float* __restrict__ lb,
    const float* __restrict__ pw, const float* __restrict__ pb,
    const float* __restrict__ dw, const float* __restrict__ db,
    const float* __restrict__ phi_b, float* __restrict__ cat_b,
    unsigned short* __restrict__ BT_hi, unsigned short* __restrict__ BT_lo)
{
    __shared__ float tile[64][65];
    const int l0 = blockIdx.x * 64, c0 = blockIdx.y * 64;
    const int li = threadIdx.x & 63, ty = threadIdx.x >> 6;
    const int l = l0 + li;
#pragma unroll 4
    for (int q = 0; q < 16; ++q) {
        int ccl = q * 4 + ty;
        int cc = c0 + ccl;
        float val;
        if (cc < 1536) {
            int i = cc >> 9, c = cc & 511, dil = 1 << i;  // dilations 1,2,4
            const float* xa = xz_b + (4096 + (long)c) * L;
            float pwv = pw[i * 512 + c], pbv = pb[i * 512 + c];
            const float* w = dw + ((long)i * 512 + c) * 3;
            float acc = db[i * 512 + c];
#pragma unroll
            for (int k = 0; k < 3; ++k) {
                int t = l + (k - 1) * dil;
                if (t >= 0 && t < L) acc += (pwv * xa[t] + pbv) * w[k];
            }
            val = acc;
        } else {
            int c = cc & 511;
            const float* xc = xz_b + (4608 + (long)c) * L;
            float acc = lb[c];
#pragma unroll
            for (int k = 0; k < 3; ++k) {
                int t = l - 1 + k;
                if (t >= 0 && t < L) acc += xc[t] * lw[c * 3 + k];
            }
            float g = 0.5f * acc * (1.f + erff(acc * 0.70710678118f));
            val = phi_b[c] * g;
        }
        cat_b[(long)cc * L + l] = val;
        tile[ccl][li] = val;
    }
    __syncthreads();
    const int ci = threadIdx.x & 63;
#pragma unroll 4
    for (int q = 0; q < 16; ++q) {
        int ll = q * 4 + ty;
        float x = tile[ci][ll];
        unsigned short h, lo;
        split1(x, h, lo);
        long o = (long)(l0 + ll) * 2048 + c0 + ci;
        BT_hi[o] = h;
        BT_lo[o] = lo;
    }
}

// ---------------------------------------------------------------------------
// LN stats, two-stage coalesced.
// ---------------------------------------------------------------------------
__global__ __launch_bounds__(256) void ln_partial_kernel(
    const float* __restrict__ cat_b, float* __restrict__ ps, float* __restrict__ pq)
{
    int l = blockIdx.x * 256 + threadIdx.x;
    int g = blockIdx.y;                      // 32 groups x 64 channels
    const float* p = cat_b + (long)g * 64 * L + l;
    float s = 0.f, q = 0.f;
#pragma unroll 8
    for (int c = 0; c < 64; ++c) {
        float v = p[(long)c * L];
        s += v;
        q = fmaf(v, v, q);
    }
    ps[g * L + l] = s;
    pq[g * L + l] = q;
}

__global__ __launch_bounds__(256) void ln_final_kernel(
    const float* __restrict__ ps, const float* __restrict__ pq,
    float* __restrict__ mu_b, float* __restrict__ rsig_b)
{
    int l = blockIdx.x * 256 + threadIdx.x;
    float s = 0.f, q = 0.f;
#pragma unroll
    for (int g = 0; g < 32; ++g) {
        s += ps[g * L + l];
        q += pq[g * L + l];
    }
    float m = s * (1.f / 2048.f);
    float var = q * (1.f / 2048.f) - m * m;
    mu_b[l] = m;
    rsig_b[l] = rsqrtf(var + 1e-5f);
}

// old single-stage LN stats (fallback path only)
__global__ __launch_bounds__(256) void ln_stats_kernel(
    const float* __restrict__ cat_b, float* __restrict__ mu_b, float* __restrict__ rsig_b)
{
    int tx = threadIdx.x & 63, ty = threadIdx.x >> 6;
    int l = blockIdx.x * 64 + tx;
    float s = 0.f, s2 = 0.f;
    for (int c = ty; c < 2048; c += 4) {
        float v = cat_b[(long)c * L + l];
        s += v;
        s2 += v * v;
    }
    __shared__ float rs[4][64], rq[4][64];
    rs[ty][tx] = s;
    rq[ty][tx] = s2;
    __syncthreads();
    if (ty == 0) {
        float S = rs[0][tx] + rs[1][tx] + rs[2][tx] + rs[3][tx];
        float Q = rq[0][tx] + rq[1][tx] + rq[2][tx] + rq[3][tx];
        float m = S * (1.f / 2048.f);
        float var = Q * (1.f / 2048.f) - m * m;
        mu_b[l] = m;
        rsig_b[l] = rsqrtf(var + 1e-5f);
    }
}

// fuse_pre: f32 wg (fallback path)
__global__ __launch_bounds__(256) void fuse_pre_kernel(
    const float* __restrict__ fw, const float* __restrict__ g,
    const float* __restrict__ lbn, const float* __restrict__ fb,
    float* __restrict__ wg, float* __restrict__ S1, float* __restrict__ S2)
{
    int o = blockIdx.x;
    float s1 = 0.f, s2 = 0.f;
    for (int c = threadIdx.x; c < 2048; c += 256) {
        float w = fw[(long)o * 2048 + c];
        float v = w * g[c];
        wg[(long)o * 2048 + c] = v;
        s1 += v;
        s2 += w * lbn[c];
    }
    __shared__ float r1[256], r2[256];
    r1[threadIdx.x] = s1;
    r2[threadIdx.x] = s2;
    __syncthreads();
    for (int st = 128; st > 0; st >>= 1) {
        if (threadIdx.x < st) {
            r1[threadIdx.x] += r1[threadIdx.x + st];
            r2[threadIdx.x] += r2[threadIdx.x + st];
        }
        __syncthreads();
    }
    if (threadIdx.x == 0) {
        S1[o] = r1[0];
        S2[o] = r2[0] + fb[o];
    }
}

// fuse_pre with bf16 hi/lo split output (MFMA path)
__global__ __launch_bounds__(256) void fuse_pre_split_kernel(
    const float* __restrict__ fw, const float* __restrict__ g,
    const float* __restrict__ lbn, const float* __restrict__ fb,
    unsigned short* __restrict__ wg_hi, unsigned short* __restrict__ wg_lo,
    float* __restrict__ S1, float* __restrict__ S2)
{
    int o = blockIdx.x;
    float s1 = 0.f, s2 = 0.f;
    for (int c = threadIdx.x; c < 2048; c += 256) {
        float w = fw[(long)o * 2048 + c];
        float v = w * g[c];
        unsigned short h, l;
        split1(v, h, l);
        wg_hi[(long)o * 2048 + c] = h;
        wg_lo[(long)o * 2048 + c] = l;
        s1 += v;
        s2 += w * lbn[c];
    }
    __shared__ float r1[256], r2[256];
    r1[threadIdx.x] = s1;
    r2[threadIdx.x] = s2;
    __syncthreads();
    for (int st = 128; st > 0; st >>= 1) {
        if (threadIdx.x < st) {
            r1[threadIdx.x] += r1[threadIdx.x + st];
            r2[threadIdx.x] += r2[threadIdx.x + st];
        }
        __syncthreads();
    }
    if (threadIdx.x == 0) {
        S1[o] = r1[0];
        S2[o] = r2[0] + fb[o];
    }
}

extern "C" void kernel_launch(void* const* d_in, const int* in_sizes, int n_in,
                              void* d_out, int out_size, void* d_ws, size_t ws_size,
                              hipStream_t stream)
{
    const float* hidden     = (const float*)d_in[0];
    const float* in_proj_w  = (const float*)d_in[1];
    const float* conv1d_w   = (const float*)d_in[2];
    const float* conv1d_b   = (const float*)d_in[3];
    const float* x_proj_w   = (const float*)d_in[4];
    const float* dt_proj_w  = (const float*)d_in[5];
    const float* dt_proj_b  = (const float*)d_in[6];
    const float* A_log      = (const float*)d_in[7];
    const float* Dvec       = (const float*)d_in[8];
    const float* out_proj_w = (const float*)d_in[9];
    const float* cb_local_w = (const float*)d_in[10];
    const float* cb_local_b = (const float*)d_in[11];
    const float* cb_global_w= (const float*)d_in[12];
    const float* cb_global_b= (const float*)d_in[13];
    const float* cb_pre_w   = (const float*)d_in[14];
    const float* cb_pre_b   = (const float*)d_in[15];
    const float* cb_dil_w   = (const float*)d_in[16];
    const float* cb_dil_b   = (const float*)d_in[17];
    const float* cb_ln_g    = (const float*)d_in[18];
    const float* cb_ln_b    = (const float*)d_in[19];
    const float* cb_fuse_w  = (const float*)d_in[20];
    const float* cb_fuse_b  = (const float*)d_in[21];

    float* ws = (float*)d_ws;
    const size_t CSZ = (size_t)2 * NCH * 1024 * 16;            // 1179648 floats

    // ---------------- MFMA-tier layout (all counts in floats) ----------------
    size_t off = 0;
    float* S1    = ws + off; off += 1024;
    float* S2    = ws + off; off += 1024;
    float* xz_b  = ws + off; off += (size_t)5120 * L;
    float* out_fb= ws + off; off += (size_t)3072 * L;
    float* cat_b = ws + off; off += (size_t)2048 * L;
    float* delta_b = cat_b;   // delta written after LN stats consumed cat
    float* xconv_b = ws + off; off += (size_t)2048 * L;
    float* xdbl_b  = ws + off; off += (size_t)128 * L;
    float* mu_b    = ws + off; off += L;
    float* rsig_b  = ws + off; off += L;
    float* phi_b   = ws + off; off += 512;
    float* lnps    = ws + off; off += (size_t)32 * L;
    float* lnpq    = ws + off; off += (size_t)32 * L;
    float* hend = ws + off; off += CSZ;
    float* pAb  = ws + off; off += CSZ;
    float* hin  = ws + off; off += CSZ;
    unsigned short* wg_hi  = (unsigned short*)(ws + off); off += (size_t)1024 * 2048 / 2;
    unsigned short* wg_lo  = (unsigned short*)(ws + off); off += (size_t)1024 * 2048 / 2;
    unsigned short* inW_hi = (unsigned short*)(ws + off); off += (size_t)5120 * 512 / 2;
    unsigned short* inW_lo = (unsigned short*)(ws + off); off += (size_t)5120 * 512 / 2;
    unsigned short* outW_hi= (unsigned short*)(ws + off); off += (size_t)512 * 3072 / 2;
    unsigned short* outW_lo= (unsigned short*)(ws + off); off += (size_t)512 * 3072 / 2;
    unsigned short* BT_hi  = (unsigned short*)(ws + off); off += (size_t)3072 * L / 2;
    unsigned short* BT_lo  = (unsigned short*)(ws + off); off += (size_t)3072 * L / 2;
    size_t need_mfma = off * sizeof(float);                    // ~183 MB

    // x_proj split-K partials alias out_fb's scan region (dead at that point)
    float* xpP = out_fb;
    // fuse partials (4 x 1024 x L) and out_proj partials (8 x 512 x L) both
    // occupy 4096*L floats = the CONTIGUOUS cat_b+xconv_b region (both dead
    // at their respective points; same-stream ordering).
    float* fsP = cat_b;
    float* opP = cat_b;

    if (ws_size >= need_mfma) {
        // ================= MFMA split-bf16 path =================
        fuse_pre_split_kernel<<<1024, 256, 0, stream>>>(
            cb_fuse_w, cb_ln_g, cb_ln_b, cb_fuse_b, wg_hi, wg_lo, S1, S2);
        split_kernel<<<(5120 * 512) / 1024, 256, 0, stream>>>(in_proj_w, inW_hi, inW_lo, 5120 * 512);
        split_kernel<<<(512 * 3072) / 1024, 256, 0, stream>>>(out_proj_w, outW_hi, outW_lo, 512 * 3072);

        for (int b = 0; b < NB; ++b) {
            const float* hid_b = hidden + (size_t)b * L * 512;
            float* out_b = (float*)d_out + (size_t)b * L * 512;

            // hidden split -> BT region ([l][d] already k-contig)
            split_kernel<<<(L * 512) / 1024, 256, 0, stream>>>(hid_b, BT_hi, BT_lo, L * 512);
            // in_proj: xz_b[e][l]
            gemm_mfma<<<dim3(5120 / 128, L / 128), 256, 0, stream>>>(
                inW_hi, inW_lo, 512, BT_hi, BT_lo, 512,
                xz_b, L, 1, 512, 0, nullptr, nullptr, nullptr, nullptr);

            // conv branch: cat + transposed bf16 split in one pass
            mean_phi_kernel<<<512, 256, 0, stream>>>(xz_b, cb_global_w, cb_global_b, phi_b);
            cat_build_bt_kernel<<<dim3(L / 64, 2048 / 64), 256, 0, stream>>>(
                xz_b, cb_local_w, cb_local_b, cb_pre_w, cb_pre_b, cb_dil_w, cb_dil_b,
                phi_b, cat_b, BT_hi, BT_lo);
            ln_partial_kernel<<<dim3(L / 256, 32), 256, 0, stream>>>(cat_b, lnps, lnpq);
            ln_final_kernel<<<L / 256, 256, 0, stream>>>(lnps, lnpq, mu_b, rsig_b);
            // fuse GEMM: split-K (4 slices of 512), 128x128 tiles
            gemm_mfma128sk<<<dim3(1024 / 128, L / 128, 4), 256, 0, stream>>>(
                wg_hi, wg_lo, 2048, BT_hi, BT_lo, 2048, fsP, 512, 1024);
            // reduce + epilogue -> BT[l][3072] cols 2048.. (bf16 split, direct)
            fuse_reduce_bt<<<L, 256, 0, stream>>>(
                fsP, mu_b, rsig_b, S1, S2, BT_hi, BT_lo);

            // mamba branch
            mamba_conv_kernel<<<(2 * 1024 * L) / 256, 256, 0, stream>>>(
                xz_b, conv1d_w, conv1d_b, xconv_b);
            xproj_partial<<<dim3(L / 64, 2, 4), 256, 0, stream>>>(
                x_proj_w, xconv_b, xpP);
            xproj_reduce<<<(2 * 64 * L / 4) / 256, 256, 0, stream>>>(xpP, xdbl_b);
            gemm_f32<<<dim3(1024 / 64, L / 64, 2), 256, 0, stream>>>(
                dt_proj_w, 32, xdbl_b, L, 0, (long)64 * L,
                delta_b, L, 1, (long)1024 * L, 1024, L, 32,
                dt_proj_b, 1, nullptr, nullptr, nullptr, nullptr);
            scan_pass1<<<dim3(64, 2, NCH), 256, 0, stream>>>(
                delta_b, xconv_b, xdbl_b, A_log, hend, pAb);
            scan_fix<<<128, 256, 0, stream>>>(hend, pAb, hin);
            // scan output -> BT[l][3072] cols 0..2047 (bf16 split, direct)
            scan_pass2_bt<<<dim3(64, 2, NCH), 256, 0, stream>>>(
                delta_b, xconv_b, xdbl_b, xz_b, A_log, Dvec, hin, BT_hi, BT_lo);

            // out_proj: split-K (8 slices of 384), 128x128 tiles -> reduce
            gemm_mfma128sk<<<dim3(512 / 128, L / 128, 8), 256, 0, stream>>>(
                outW_hi, outW_lo, 3072, BT_hi, BT_lo, 3072, opP, 384, 512);
            out_reduce<<<(512 * L / 4) / 256, 256, 0, stream>>>(opP, out_b);
        }
        return;
    }

    // ================= fallback: f32 path (dedicated chunk buffers only) =====
    off = 0;
    float* wg    = ws + off; off += (size_t)1024 * 2048;
    S1    = ws + off; off += 1024;
    S2    = ws + off; off += 1024;
    xz_b  = ws + off; off += (size_t)5120 * L;
    out_fb= ws + off; off += (size_t)3072 * L;
    cat_b = ws + off; off += (size_t)2048 * L;
    delta_b = cat_b;
    xconv_b = ws + off; off += (size_t)2048 * L;
    xdbl_b  = ws + off; off += (size_t)128 * L;
    mu_b    = ws + off; off += L;
    rsig_b  = ws + off; off += L;
    phi_b   = ws + off; off += 512;
    hend = ws + off; off += CSZ;
    pAb  = ws + off; off += CSZ;
    hin  = ws + off; off += CSZ;
    if (ws_size < off * sizeof(float)) return;  // clean failure (diagnostic)

    fuse_pre_kernel<<<1024, 256, 0, stream>>>(cb_fuse_w, cb_ln_g, cb_ln_b, cb_fuse_b, wg, S1, S2);

    for (int b = 0; b < NB; ++b) {
        const float* hid_b = hidden + (size_t)b * L * 512;
        float* out_b = (float*)d_out + (size_t)b * L * 512;

        gemm_f32<<<dim3(5120 / 64, L / 64, 1), 256, 0, stream>>>(
            in_proj_w, 512, hid_b, 512, 1, 0,
            xz_b, L, 1, 0, 5120, L, 512,
            nullptr, 0, nullptr, nullptr, nullptr, nullptr);

        mean_phi_kernel<<<512, 256, 0, stream>>>(xz_b, cb_global_w, cb_global_b, phi_b);
        cat_build_kernel<<<(2048 * L) / 256, 256, 0, stream>>>(
            xz_b, cb_local_w, cb_local_b, cb_pre_w, cb_pre_b, cb_dil_w, cb_dil_b, phi_b, cat_b);
        ln_stats_kernel<<<L / 64, 256, 0, stream>>>(cat_b, mu_b, rsig_b);
        gemm_f32<<<dim3(1024 / 64, L / 64, 1), 256, 0, stream>>>(
            wg, 2048, cat_b, L, 0, 0,
            out_fb + (long)2048 * L, L, 1, 0, 1024, L, 2048,
            nullptr, 2, mu_b, rsig_b, S1, S2);

        mamba_conv_kernel<<<(2 * 1024 * L) / 256, 256, 0, stream>>>(
            xz_b, conv1d_w, conv1d_b, xconv_b);
        gemm_f32<<<dim3(1, L / 64, 2), 256, 0, stream>>>(
            x_proj_w, 1024, xconv_b, L, 0, (long)1024 * L,
            xdbl_b, L, 1, (long)64 * L, 64, L, 1024,
            nullptr, 0, nullptr, nullptr, nullptr, nullptr);
        gemm_f32<<<dim3(1024 / 64, L / 64, 2), 256, 0, stream>>>(
            dt_proj_w, 32, xdbl_b, L, 0, (long)64 * L,
            delta_b, L, 1, (long)1024 * L, 1024, L, 32,
            dt_proj_b, 1, nullptr, nullptr, nullptr, nullptr);
        scan_pass1<<<dim3(64, 2, NCH), 256, 0, stream>>>(
            delta_b, xconv_b, xdbl_b, A_log, hend, pAb);
        scan_fix<<<128, 256, 0, stream>>>(hend, pAb, hin);
        scan_pass2<<<dim3(64, 2, NCH), 256, 0, stream>>>(
            delta_b, xconv_b, xdbl_b, xz_b, A_log, Dvec, hin, out_fb);

        gemm_f32<<<dim3(512 / 64, L / 64, 1), 256, 0, stream>>>(
            out_proj_w, 3072, out_fb, L, 0, 0,
            out_b, 1, 512, 0, 512, L, 3072,
            nullptr, 0, nullptr, nullptr, nullptr, nullptr);
    }
}

// Round 30
// 1224.252 us; speedup vs baseline: 1.0132x; 1.0132x over previous
//
#include <hip/hip_runtime.h>
#include <math.h>

#define L 2304
#define NB 4
#define NCH 36
#define STILE 64
#define SPAD 68
#define DLU_PAD 130   // 2*STILE + 2

typedef __attribute__((ext_vector_type(8))) short short8v;
typedef __attribute__((ext_vector_type(4))) float f32x4;

__device__ inline unsigned short f2bf(float x) {
    unsigned u = __float_as_uint(x);
    return (unsigned short)((u + 0x7fffu + ((u >> 16) & 1u)) >> 16);
}
__device__ inline void split1(float x, unsigned short& h, unsigned short& l) {
    h = f2bf(x);
    float hf = __uint_as_float((unsigned)h << 16);
    l = f2bf(x - hf);
}

// async global->LDS 16B copy (linear dest = wave-uniform base + lane*16)
__device__ __forceinline__ void gload16(const unsigned short* g, unsigned short* l)
{
    __builtin_amdgcn_global_load_lds(
        (const __attribute__((address_space(1))) unsigned int*)g,
        (__attribute__((address_space(3))) unsigned int*)l, 16, 0, 0);
}

// 16-lane sum-reduce on the VALU pipe via DPP (no DS ops).
__device__ inline float row_reduce16(float v) {
    v += __int_as_float(__builtin_amdgcn_update_dpp(0, __float_as_int(v), 0xB1, 0xF, 0xF, true));
    v += __int_as_float(__builtin_amdgcn_update_dpp(0, __float_as_int(v), 0x4E, 0xF, 0xF, true));
    v += __int_as_float(__builtin_amdgcn_update_dpp(0, __float_as_int(v), 0x124, 0xF, 0xF, true));
    v += __int_as_float(__builtin_amdgcn_update_dpp(0, __float_as_int(v), 0x128, 0xF, 0xF, true));
    return v;
}

// ---------------------------------------------------------------------------
// f32 -> (hi,lo) bf16 split, layout-preserving. n multiple of 1024.
// ---------------------------------------------------------------------------
__global__ __launch_bounds__(256) void split_kernel(
    const float* __restrict__ src, unsigned short* __restrict__ hi,
    unsigned short* __restrict__ lo, int n)
{
    int i = (blockIdx.x * 256 + threadIdx.x) * 4;
    if (i >= n) return;
    float4 v = *(const float4*)(src + i);
    unsigned short h0, h1, h2, h3, l0, l1, l2, l3;
    split1(v.x, h0, l0); split1(v.y, h1, l1);
    split1(v.z, h2, l2); split1(v.w, h3, l3);
    ushort4 hv; hv.x = h0; hv.y = h1; hv.z = h2; hv.w = h3;
    ushort4 lv; lv.x = l0; lv.y = l1; lv.z = l2; lv.w = l3;
    *(ushort4*)(hi + i) = hv;
    *(ushort4*)(lo + i) = lv;
}

// ---------------------------------------------------------------------------
// Transposing split: src[C][L] f32 -> hiT/loT[L][C] bf16. (fallback path use)
// ---------------------------------------------------------------------------
__global__ __launch_bounds__(256) void split_t_kernel(
    const float* __restrict__ src, unsigned short* __restrict__ hiT,
    unsigned short* __restrict__ loT, int C)
{
    __shared__ float tile[64][65];
    const int l0 = blockIdx.x * 64, c0 = blockIdx.y * 64;
    const int li = threadIdx.x & 63, q = threadIdx.x >> 6;
    for (int cc = q; cc < 64; cc += 4)
        tile[cc][li] = src[(long)(c0 + cc) * L + l0 + li];
    __syncthreads();
    const int ci = threadIdx.x & 63;
    for (int ll = q; ll < 64; ll += 4) {
        float x = tile[ci][ll];
        unsigned short h, l;
        split1(x, h, l);
        long o = (long)(l0 + ll) * C + c0 + ci;
        hiT[o] = h;
        loT[o] = l;
    }
}

// ---------------------------------------------------------------------------
// Split-bf16 MFMA GEMM, 128x128 tile: C[m,n] = sum_k A[m,k]*B^T[n,k].
// gload_lds staging with XOR swizzle; natural block mapping (gridDim.x%8==0).
// ---------------------------------------------------------------------------
__global__ __launch_bounds__(256) void gemm_mfma(
    const unsigned short* __restrict__ Ahi, const unsigned short* __restrict__ Alo, int lda,
    const unsigned short* __restrict__ Bhi, const unsigned short* __restrict__ Blo, int ldb,
    float* __restrict__ C, long cms, long cns, int K, int act,
    const float* __restrict__ emu, const float* __restrict__ ers,
    const float* __restrict__ es1, const float* __restrict__ es2)
{
    __shared__ unsigned short Ah[128 * 32], Al[128 * 32], Bh[128 * 32], Bl[128 * 32];
    const int tid = threadIdx.x;
    const int lane = tid & 63, wave = tid >> 6;
    const int wm = (wave >> 1) * 64, wn = (wave & 1) * 64;
    const int m0 = blockIdx.x * 128, n0 = blockIdx.y * 128;
    const int rowS = tid >> 2;
    const int cS = ((tid & 3) ^ ((tid >> 3) & 3)) * 8;
    const unsigned short* gAh0 = Ahi + (long)(m0 + rowS) * lda + cS;
    const unsigned short* gAl0 = Alo + (long)(m0 + rowS) * lda + cS;
    const unsigned short* gBh0 = Bhi + (long)(n0 + rowS) * ldb + cS;
    const unsigned short* gBl0 = Blo + (long)(n0 + rowS) * ldb + cS;
    const long a64 = (long)64 * lda, b64 = (long)64 * ldb;
    unsigned short* lAh0 = Ah + tid * 8;  unsigned short* lAh1 = Ah + 2048 + tid * 8;
    unsigned short* lAl0 = Al + tid * 8;  unsigned short* lAl1 = Al + 2048 + tid * 8;
    unsigned short* lBh0 = Bh + tid * 8;  unsigned short* lBh1 = Bh + 2048 + tid * 8;
    unsigned short* lBl0 = Bl + tid * 8;  unsigned short* lBl1 = Bl + 2048 + tid * 8;
    const int fr = lane & 15;
    const int chq = (((lane >> 4) ^ ((fr >> 1) & 3)) << 3);

    f32x4 acc[4][4];
#pragma unroll
    for (int i = 0; i < 4; ++i)
#pragma unroll
        for (int j = 0; j < 4; ++j) acc[i][j] = (f32x4){0.f, 0.f, 0.f, 0.f};

    for (int k0 = 0; k0 < K; k0 += 32) {
        gload16(gAh0 + k0, lAh0); gload16(gAh0 + a64 + k0, lAh1);
        gload16(gAl0 + k0, lAl0); gload16(gAl0 + a64 + k0, lAl1);
        gload16(gBh0 + k0, lBh0); gload16(gBh0 + b64 + k0, lBh1);
        gload16(gBl0 + k0, lBl0); gload16(gBl0 + b64 + k0, lBl1);
        __syncthreads();
        short8v bhf[4], blf[4];
#pragma unroll
        for (int nf = 0; nf < 4; ++nf) {
            bhf[nf] = *(const short8v*)&Bh[(wn + nf * 16 + fr) * 32 + chq];
            blf[nf] = *(const short8v*)&Bl[(wn + nf * 16 + fr) * 32 + chq];
        }
#pragma unroll
        for (int mf = 0; mf < 4; ++mf) {
            short8v ah = *(const short8v*)&Ah[(wm + mf * 16 + fr) * 32 + chq];
            short8v al = *(const short8v*)&Al[(wm + mf * 16 + fr) * 32 + chq];
#pragma unroll
            for (int nf = 0; nf < 4; ++nf) {
                acc[mf][nf] = __builtin_amdgcn_mfma_f32_16x16x32_bf16(ah, bhf[nf], acc[mf][nf], 0, 0, 0);
                acc[mf][nf] = __builtin_amdgcn_mfma_f32_16x16x32_bf16(ah, blf[nf], acc[mf][nf], 0, 0, 0);
                acc[mf][nf] = __builtin_amdgcn_mfma_f32_16x16x32_bf16(al, bhf[nf], acc[mf][nf], 0, 0, 0);
            }
        }
        __syncthreads();
    }
    const int rb = (lane >> 4) * 4;
#pragma unroll
    for (int mf = 0; mf < 4; ++mf) {
#pragma unroll
        for (int nf = 0; nf < 4; ++nf) {
            int n = n0 + wn + nf * 16 + fr;
            int mb = m0 + wm + mf * 16 + rb;
            if (cms == 1) {
                float4 r;
                r.x = acc[mf][nf][0]; r.y = acc[mf][nf][1];
                r.z = acc[mf][nf][2]; r.w = acc[mf][nf][3];
                *(float4*)(C + (long)n * cns + mb) = r;
            } else {
#pragma unroll
                for (int r = 0; r < 4; ++r) {
                    int m = mb + r;
                    float v = acc[mf][nf][r];
                    if (act == 2) v = (v - emu[n] * es1[m]) * ers[n] + es2[m];
                    C[(long)m * cms + n] = v;
                }
            }
        }
    }
}

// ---------------------------------------------------------------------------
// Split-K 128x128-tile MFMA GEMM: blockIdx.z = K-slice. 48 MFMA per K-step.
// gload_lds staging + XCD-aware bijective block swizzle.
// ---------------------------------------------------------------------------
__global__ __launch_bounds__(256) void gemm_mfma128sk(
    const unsigned short* __restrict__ Ahi, const unsigned short* __restrict__ Alo, int lda,
    const unsigned short* __restrict__ Bhi, const unsigned short* __restrict__ Blo, int ldb,
    float* __restrict__ P, int KS, int Mstride)
{
    __shared__ unsigned short Ah[128 * 32], Al[128 * 32], Bh[128 * 32], Bl[128 * 32];
    const int tid = threadIdx.x;
    const int lane = tid & 63, wave = tid >> 6;
    const int wm = (wave >> 1) * 64, wn = (wave & 1) * 64;
    const int nwg = gridDim.x * gridDim.y * gridDim.z;
    const int bid = blockIdx.x + gridDim.x * (blockIdx.y + gridDim.y * blockIdx.z);
    const int cpx = nwg >> 3;
    const int swz = (bid & 7) * cpx + (bid >> 3);
    const int bx = swz % gridDim.x;
    const int rest = swz / gridDim.x;
    const int by = rest % gridDim.y;
    const int sl = rest / gridDim.y;
    const int m0 = bx * 128, n0 = by * 128;
    const int kbase = sl * KS;
    const int rowS = tid >> 2;
    const int cS = ((tid & 3) ^ ((tid >> 3) & 3)) * 8;
    const unsigned short* gAh0 = Ahi + (long)(m0 + rowS) * lda + kbase + cS;
    const unsigned short* gAl0 = Alo + (long)(m0 + rowS) * lda + kbase + cS;
    const unsigned short* gBh0 = Bhi + (long)(n0 + rowS) * ldb + kbase + cS;
    const unsigned short* gBl0 = Blo + (long)(n0 + rowS) * ldb + kbase + cS;
    const long a64 = (long)64 * lda, b64 = (long)64 * ldb;
    unsigned short* lAh0 = Ah + tid * 8;  unsigned short* lAh1 = Ah + 2048 + tid * 8;
    unsigned short* lAl0 = Al + tid * 8;  unsigned short* lAl1 = Al + 2048 + tid * 8;
    unsigned short* lBh0 = Bh + tid * 8;  unsigned short* lBh1 = Bh + 2048 + tid * 8;
    unsigned short* lBl0 = Bl + tid * 8;  unsigned short* lBl1 = Bl + 2048 + tid * 8;
    const int fr = lane & 15;
    const int chq = (((lane >> 4) ^ ((fr >> 1) & 3)) << 3);

    f32x4 acc[4][4];
#pragma unroll
    for (int i = 0; i < 4; ++i)
#pragma unroll
        for (int j = 0; j < 4; ++j) acc[i][j] = (f32x4){0.f, 0.f, 0.f, 0.f};

    for (int k0 = 0; k0 < KS; k0 += 32) {
        gload16(gAh0 + k0, lAh0); gload16(gAh0 + a64 + k0, lAh1);
        gload16(gAl0 + k0, lAl0); gload16(gAl0 + a64 + k0, lAl1);
        gload16(gBh0 + k0, lBh0); gload16(gBh0 + b64 + k0, lBh1);
        gload16(gBl0 + k0, lBl0); gload16(gBl0 + b64 + k0, lBl1);
        __syncthreads();
        short8v bhf[4], blf[4];
#pragma unroll
        for (int nf = 0; nf < 4; ++nf) {
            bhf[nf] = *(const short8v*)&Bh[(wn + nf * 16 + fr) * 32 + chq];
            blf[nf] = *(const short8v*)&Bl[(wn + nf * 16 + fr) * 32 + chq];
        }
#pragma unroll
        for (int mf = 0; mf < 4; ++mf) {
            short8v ah = *(const short8v*)&Ah[(wm + mf * 16 + fr) * 32 + chq];
            short8v al = *(const short8v*)&Al[(wm + mf * 16 + fr) * 32 + chq];
#pragma unroll
            for (int nf = 0; nf < 4; ++nf) {
                acc[mf][nf] = __builtin_amdgcn_mfma_f32_16x16x32_bf16(ah, bhf[nf], acc[mf][nf], 0, 0, 0);
                acc[mf][nf] = __builtin_amdgcn_mfma_f32_16x16x32_bf16(ah, blf[nf], acc[mf][nf], 0, 0, 0);
                acc[mf][nf] = __builtin_amdgcn_mfma_f32_16x16x32_bf16(al, bhf[nf], acc[mf][nf], 0, 0, 0);
            }
        }
        __syncthreads();
    }
    const int rb = (lane >> 4) * 4;
    float* Pp = P + (long)sl * Mstride * L;
#pragma unroll
    for (int mf = 0; mf < 4; ++mf) {
#pragma unroll
        for (int nf = 0; nf < 4; ++nf) {
            int n = n0 + wn + nf * 16 + fr;
            int mb = m0 + wm + mf * 16 + rb;
            float4 r;
            r.x = acc[mf][nf][0]; r.y = acc[mf][nf][1];
            r.z = acc[mf][nf][2]; r.w = acc[mf][nf][3];
            *(float4*)(Pp + (long)n * Mstride + mb) = r;
        }
    }
}

// out_proj reduce: sum 8 slices of P[sl][n][512]
__global__ __launch_bounds__(256) void out_reduce(
    const float* __restrict__ P, float* __restrict__ out)
{
    const long E = (long)512 * L;
    long i = ((long)blockIdx.x * 256 + threadIdx.x) * 4;
    float4 r = *(const float4*)(P + i);
#pragma unroll
    for (int s = 1; s < 8; ++s) {
        float4 a = *(const float4*)(P + (long)s * E + i);
        r.x += a.x; r.y += a.y; r.z += a.z; r.w += a.w;
    }
    *(float4*)(out + i) = r;
}

// ---------------------------------------------------------------------------
// Fuse split-K reduce -> direct bf16-split transposed B write.
// P[sl][l][1024] (already l-major); sum 4 slices, LN-affine epilogue,
// split1, write BT[l][3072] columns 2048..3071.
// ---------------------------------------------------------------------------
__global__ __launch_bounds__(256) void fuse_reduce_bt(
    const float* __restrict__ P,
    const float* __restrict__ emu, const float* __restrict__ ers,
    const float* __restrict__ es1, const float* __restrict__ es2,
    unsigned short* __restrict__ BT_hi, unsigned short* __restrict__ BT_lo)
{
    const long E = (long)1024 * L;
    long idx = (long)blockIdx.x * 256 + threadIdx.x;   // over L*256
    int l = (int)(idx >> 8);
    int dq = (int)(idx & 255) * 4;
    long base = (long)l * 1024 + dq;
    float4 a = *(const float4*)(P + base);
    float4 b = *(const float4*)(P + E + base);
    float4 c = *(const float4*)(P + 2 * E + base);
    float4 d = *(const float4*)(P + 3 * E + base);
    float v[4];
    v[0] = (a.x + b.x) + (c.x + d.x);
    v[1] = (a.y + b.y) + (c.y + d.y);
    v[2] = (a.z + b.z) + (c.z + d.z);
    v[3] = (a.w + b.w) + (c.w + d.w);
    float mu = emu[l], rs = ers[l];
    unsigned short hv[4], lv[4];
#pragma unroll
    for (int j = 0; j < 4; ++j) {
        int m = dq + j;
        float x = (v[j] - mu * es1[m]) * rs + es2[m];
        split1(x, hv[j], lv[j]);
    }
    long o = (long)l * 3072 + 2048 + dq;
    ushort4 h4; h4.x = hv[0]; h4.y = hv[1]; h4.z = hv[2]; h4.w = hv[3];
    ushort4 l4; l4.x = lv[0]; l4.y = lv[1]; l4.z = lv[2]; l4.w = lv[3];
    *(ushort4*)(BT_hi + o) = h4;
    *(ushort4*)(BT_lo + o) = l4;
}

// ---------------------------------------------------------------------------
// Generic f32 tiled GEMM (dt_proj and fallback).
// ---------------------------------------------------------------------------
__global__ __launch_bounds__(256) void gemm_f32(
    const float* __restrict__ A, int lda,
    const float* __restrict__ B, long ldb, int b_nk, long bbs,
    float* __restrict__ C, long cms, long cns, long cbs,
    int M, int N, int K,
    const float* __restrict__ bias, int act,
    const float* __restrict__ emu, const float* __restrict__ ers,
    const float* __restrict__ es1, const float* __restrict__ es2)
{
    __shared__ float As[16][65];
    __shared__ float Bs[16][65];
    const int tid = threadIdx.x;
    const int tx = tid & 15, ty = tid >> 4;
    const int m0 = blockIdx.x * 64, n0 = blockIdx.y * 64;
    const int bz = blockIdx.z;
    const float* Bb = B + (long)bz * bbs;
    float acc[4][4];
#pragma unroll
    for (int i = 0; i < 4; ++i)
#pragma unroll
        for (int j = 0; j < 4; ++j) acc[i][j] = 0.f;

    for (int k0 = 0; k0 < K; k0 += 16) {
        {
            int m = tid >> 2, kq = (tid & 3) << 2;
            float4 v = *(const float4*)(A + (long)(m0 + m) * lda + (k0 + kq));
            As[kq + 0][m] = v.x; As[kq + 1][m] = v.y; As[kq + 2][m] = v.z; As[kq + 3][m] = v.w;
        }
        if (b_nk) {
            int n = tid >> 2, kq = (tid & 3) << 2;
            float4 v = *(const float4*)(Bb + (long)(n0 + n) * ldb + (k0 + kq));
            Bs[kq + 0][n] = v.x; Bs[kq + 1][n] = v.y; Bs[kq + 2][n] = v.z; Bs[kq + 3][n] = v.w;
        } else {
            int k = tid >> 4, nq = (tid & 15) << 2;
            float4 v = *(const float4*)(Bb + (long)(k0 + k) * ldb + (n0 + nq));
            Bs[k][nq + 0] = v.x; Bs[k][nq + 1] = v.y; Bs[k][nq + 2] = v.z; Bs[k][nq + 3] = v.w;
        }
        __syncthreads();
#pragma unroll
        for (int kk = 0; kk < 16; ++kk) {
            float a[4], b[4];
#pragma unroll
            for (int i = 0; i < 4; ++i) a[i] = As[kk][ty * 4 + i];
#pragma unroll
            for (int j = 0; j < 4; ++j) b[j] = Bs[kk][tx * 4 + j];
#pragma unroll
            for (int i = 0; i < 4; ++i)
#pragma unroll
                for (int j = 0; j < 4; ++j) acc[i][j] = fmaf(a[i], b[j], acc[i][j]);
        }
        __syncthreads();
    }
#pragma unroll
    for (int i = 0; i < 4; ++i) {
        int m = m0 + ty * 4 + i;
        float bs = bias ? bias[m] : 0.f;
        float s1 = es1 ? es1[m] : 0.f;
        float s2 = es2 ? es2[m] : 0.f;
#pragma unroll
        for (int j = 0; j < 4; ++j) {
            int n = n0 + tx * 4 + j;
            float v = acc[i][j] + bs;
            if (act == 1) v = (v > 20.f) ? v : log1pf(expf(v));
            else if (act == 2) {
                float mu = emu[n];
                float rs = ers[n];
                v = (v - mu * s1) * rs + s2;
            }
            C[(long)bz * cbs + (long)m * cms + (long)n * cns] = v;
        }
    }
}

// ---------------------------------------------------------------------------
// x_proj split-K: partial[sl][dir][64][L] = W[64, sl*256..+256) . xconv slice
// ---------------------------------------------------------------------------
__global__ __launch_bounds__(256) void xproj_partial(
    const float* __restrict__ W, const float* __restrict__ xconv,
    float* __restrict__ P)
{
    __shared__ float As[16][65];
    __shared__ float Bs[16][65];
    const int tid = threadIdx.x;
    const int tx = tid & 15, ty = tid >> 4;
    const int n0 = blockIdx.x * 64;
    const int dir = blockIdx.y, sl = blockIdx.z;
    const float* A = W + sl * 256;                                  // lda=1024
    const float* B = xconv + ((long)dir * 1024 + sl * 256) * L;     // [256][L]
    float* Pp = P + ((long)sl * 2 + dir) * 64 * L;
    float acc[4][4];
#pragma unroll
    for (int i = 0; i < 4; ++i)
#pragma unroll
        for (int j = 0; j < 4; ++j) acc[i][j] = 0.f;

    for (int k0 = 0; k0 < 256; k0 += 16) {
        {
            int m = tid >> 2, kq = (tid & 3) << 2;
            float4 v = *(const float4*)(A + (long)m * 1024 + (k0 + kq));
            As[kq + 0][m] = v.x; As[kq + 1][m] = v.y; As[kq + 2][m] = v.z; As[kq + 3][m] = v.w;
        }
        {
            int k = tid >> 4, nq = (tid & 15) << 2;
            float4 v = *(const float4*)(B + (long)(k0 + k) * L + (n0 + nq));
            Bs[k][nq + 0] = v.x; Bs[k][nq + 1] = v.y; Bs[k][nq + 2] = v.z; Bs[k][nq + 3] = v.w;
        }
        __syncthreads();
#pragma unroll
        for (int kk = 0; kk < 16; ++kk) {
            float a[4], b[4];
#pragma unroll
            for (int i = 0; i < 4; ++i) a[i] = As[kk][ty * 4 + i];
#pragma unroll
            for (int j = 0; j < 4; ++j) b[j] = Bs[kk][tx * 4 + j];
#pragma unroll
            for (int i = 0; i < 4; ++i)
#pragma unroll
                for (int j = 0; j < 4; ++j) acc[i][j] = fmaf(a[i], b[j], acc[i][j]);
        }
        __syncthreads();
    }
#pragma unroll
    for (int i = 0; i < 4; ++i) {
        int m = ty * 4 + i;
        float4 r;
        r.x = acc[i][0]; r.y = acc[i][1]; r.z = acc[i][2]; r.w = acc[i][3];
        *(float4*)(Pp + (long)m * L + n0 + tx * 4) = r;
    }
}

__global__ __launch_bounds__(256) void xproj_reduce(
    const float* __restrict__ P, float* __restrict__ xdbl)
{
    const long E = (long)2 * 64 * L;                 // 294912
    long i = ((long)blockIdx.x * 256 + threadIdx.x) * 4;
    float4 a = *(const float4*)(P + i);
    float4 b = *(const float4*)(P + E + i);
    float4 c = *(const float4*)(P + 2 * E + i);
    float4 d = *(const float4*)(P + 3 * E + i);
    float4 r;
    r.x = (a.x + b.x) + (c.x + d.x);
    r.y = (a.y + b.y) + (c.y + d.y);
    r.z = (a.z + b.z) + (c.z + d.z);
    r.w = (a.w + b.w) + (c.w + d.w);
    *(float4*)(xdbl + i) = r;
}

// ---------------------------------------------------------------------------
// Mamba causal depthwise conv (k=4) + bias + SiLU, per batch.
// ---------------------------------------------------------------------------
__global__ __launch_bounds__(256) void mamba_conv_kernel(
    const float* __restrict__ xz_b, const float* __restrict__ w,
    const float* __restrict__ bias, float* __restrict__ xout)
{
    long idx = (long)blockIdx.x * 256 + threadIdx.x;   // over 2*1024*L
    int l = (int)(idx % L);
    long r = idx / L;
    int d = (int)(r % 1024);
    int dir = (int)(r / 1024);
    const float* src = xz_b + ((dir ? 2048 : 0) + (long)d) * L;
    float acc = bias[d];
#pragma unroll
    for (int j = 0; j < 4; ++j) {
        int t = l - 3 + j;
        if (t >= 0) {
            float v = dir ? src[L - 1 - t] : src[t];
            acc = fmaf(w[d * 4 + j], v, acc);
        }
    }
    xout[idx] = acc / (1.f + expf(-acc));  // silu
}

// ---------------------------------------------------------------------------
// Chunked selective scan. DS-minimized: interleaved float2 LDS rows
// (1 ds_read_b64 for dl/u, 1 for B/C) and DPP-based 16-lane reduction.
// ---------------------------------------------------------------------------
__global__ __launch_bounds__(256) void scan_pass1(
    const float* __restrict__ delta_b, const float* __restrict__ xconv_b,
    const float* __restrict__ xdbl_b, const float* __restrict__ A_log,
    float* __restrict__ hend, float* __restrict__ pAb)
{
    __shared__ float s_dlu[16][DLU_PAD];
    __shared__ float s_B[16][SPAD];
    const int tid = threadIdx.x;
    const int dir = blockIdx.y, ch = blockIdx.z;
    const int n = tid & 15, dloc = tid >> 4;
    const int d0 = blockIdx.x * 16;
    const int d = d0 + dloc;
    const int t0 = ch * STILE;
    const float Adn = -expf(A_log[d * 16 + n]);
    const float* dl_p = delta_b + ((long)dir * 1024 + d0) * L;
    const float* u_p  = xconv_b + ((long)dir * 1024 + d0) * L;
    const float* B_p  = xdbl_b + ((long)dir * 64 + 32) * L;
    const int lch = tid >> 4, lq = tid & 15;
    {
        float4 a = *(const float4*)(dl_p + (long)lch * L + t0 + lq * 4);
        float4 b = *(const float4*)(u_p + (long)lch * L + t0 + lq * 4);
        float4 w0; w0.x = a.x; w0.y = b.x; w0.z = a.y; w0.w = b.y;
        float4 w1; w1.x = a.z; w1.y = b.z; w1.z = a.w; w1.w = b.w;
        *(float4*)&s_dlu[lch][lq * 8] = w0;
        *(float4*)&s_dlu[lch][lq * 8 + 4] = w1;
        float4 v = *(const float4*)(B_p + (long)lch * L + t0 + lq * 4);
        *(float4*)&s_B[lch][lq * 4] = v;
    }
    __syncthreads();
    float h = 0.f, p = 1.f;
#pragma unroll 4
    for (int tt = 0; tt < STILE; ++tt) {
        float2 dlu = *(const float2*)&s_dlu[dloc][tt * 2];
        float Bv = s_B[n][tt];
        float dA = __expf(dlu.x * Adn);
        h = fmaf(dA, h, dlu.x * dlu.y * Bv);
        p *= dA;
    }
    long sidx = (((long)dir * NCH + ch) * 1024 + d) * 16 + n;
    hend[sidx] = h;
    pAb[sidx] = p;
}

__global__ __launch_bounds__(256) void scan_fix(
    const float* __restrict__ hend, const float* __restrict__ pAb,
    float* __restrict__ hin)
{
    int tid = blockIdx.x * 256 + threadIdx.x;      // 32768 = 2*1024*16
    int dir = tid >> 14;
    int rest = tid & 16383;                        // d*16+n
    float h = 0.f;
#pragma unroll
    for (int c = 0; c < NCH; ++c) {
        long idx = (((long)dir * NCH + c) << 14) + rest;
        hin[idx] = h;
        h = hend[idx] + pAb[idx] * h;
    }
}

// MFMA-path scan pass 2: writes bf16-split transposed B directly into
// BT[l][3072] columns 0..2047.
__global__ __launch_bounds__(256) void scan_pass2_bt(
    const float* __restrict__ delta_b, const float* __restrict__ xconv_b,
    const float* __restrict__ xdbl_b, const float* __restrict__ xz_b,
    const float* __restrict__ A_log, const float* __restrict__ Dvec,
    const float* __restrict__ hin,
    unsigned short* __restrict__ BT_hi, unsigned short* __restrict__ BT_lo)
{
    __shared__ float s_dlu[16][DLU_PAD];   // (dl,u) pairs; dl slot reused for y
    __shared__ float s_BC[16][DLU_PAD];    // (B,C) pairs
    const int tid = threadIdx.x;
    const int dir = blockIdx.y, ch = blockIdx.z;
    const int n = tid & 15, dloc = tid >> 4;
    const int d0 = blockIdx.x * 16;
    const int d = d0 + dloc;
    const int t0 = ch * STILE;
    const int opos0 = dir ? (L - STILE - t0) : t0;
    const float Adn = -expf(A_log[d * 16 + n]);
    const float Dd = Dvec[d];
    const float* dl_p = delta_b + ((long)dir * 1024 + d0) * L;
    const float* u_p  = xconv_b + ((long)dir * 1024 + d0) * L;
    const float* B_p  = xdbl_b + ((long)dir * 64 + 32) * L;
    const float* C_p  = xdbl_b + ((long)dir * 64 + 48) * L;
    const float* z_base = xz_b + ((dir ? 3072 : 1024) + (long)d0) * L;  // z[dloc][l]
    const int lch = tid >> 4, lq = tid & 15;
    {
        float4 a = *(const float4*)(dl_p + (long)lch * L + t0 + lq * 4);
        float4 b = *(const float4*)(u_p + (long)lch * L + t0 + lq * 4);
        float4 w0; w0.x = a.x; w0.y = b.x; w0.z = a.y; w0.w = b.y;
        float4 w1; w1.x = a.z; w1.y = b.z; w1.z = a.w; w1.w = b.w;
        *(float4*)&s_dlu[lch][lq * 8] = w0;
        *(float4*)&s_dlu[lch][lq * 8 + 4] = w1;
        float4 c = *(const float4*)(B_p + (long)lch * L + t0 + lq * 4);
        float4 e = *(const float4*)(C_p + (long)lch * L + t0 + lq * 4);
        float4 x0; x0.x = c.x; x0.y = e.x; x0.z = c.y; x0.w = e.y;
        float4 x1; x1.x = c.z; x1.y = e.z; x1.z = c.w; x1.w = e.w;
        *(float4*)&s_BC[lch][lq * 8] = x0;
        *(float4*)&s_BC[lch][lq * 8 + 4] = x1;
    }
    __syncthreads();   // s_BC rows are read cross-wave
    float h = hin[(((long)dir * NCH + ch) * 1024 + d) * 16 + n];
#pragma unroll 4
    for (int tt = 0; tt < STILE; ++tt) {
        float2 dlu = *(const float2*)&s_dlu[dloc][tt * 2];
        float2 bc = *(const float2*)&s_BC[n][tt * 2];
        float dA = __expf(dlu.x * Adn);
        h = fmaf(dA, h, dlu.x * dlu.y * bc.x);
        float y = row_reduce16(h * bc.y);
        if (n == 0) s_dlu[dloc][tt * 2] = y + Dd * dlu.y;
    }
    __syncthreads();   // store phase reads s_dlu rows cross-wave
    {
        const int p = tid >> 2;              // local output position 0..63
        const int dq = (tid & 3) * 4;        // 4 channels per thread
        const int l = opos0 + p;
        const int cbase = (dir ? 1024 : 0) + d0;
        const int yi = (dir ? 63 - p : p) * 2;
        unsigned short hv[4], lv[4];
#pragma unroll
        for (int j = 0; j < 4; ++j) {
            int dl = dq + j;
            float y = s_dlu[dl][yi];
            float z = z_base[(long)dl * L + l];
            float v = y * (z / (1.f + __expf(-z)));
            split1(v, hv[j], lv[j]);
        }
        long o = (long)l * 3072 + cbase + dq;
        ushort4 h4; h4.x = hv[0]; h4.y = hv[1]; h4.z = hv[2]; h4.w = hv[3];
        ushort4 l4; l4.x = lv[0]; l4.y = lv[1]; l4.z = lv[2]; l4.w = lv[3];
        *(ushort4*)(BT_hi + o) = h4;
        *(ushort4*)(BT_lo + o) = l4;
    }
}

// f32 scan pass 2 (fallback path only)
__global__ __launch_bounds__(256) void scan_pass2(
    const float* __restrict__ delta_b, const float* __restrict__ xconv_b,
    const float* __restrict__ xdbl_b, const float* __restrict__ xz_b,
    const float* __restrict__ A_log, const float* __restrict__ Dvec,
    const float* __restrict__ hin, float* __restrict__ out_fb)
{
    __shared__ float s_dlu[16][DLU_PAD];
    __shared__ float s_BC[16][DLU_PAD];
    const int tid = threadIdx.x;
    const int dir = blockIdx.y, ch = blockIdx.z;
    const int n = tid & 15, dloc = tid >> 4;
    const int d0 = blockIdx.x * 16;
    const int d = d0 + dloc;
    const int t0 = ch * STILE;
    const int opos0 = dir ? (L - STILE - t0) : t0;
    const float Adn = -expf(A_log[d * 16 + n]);
    const float Dd = Dvec[d];
    const float* dl_p = delta_b + ((long)dir * 1024 + d0) * L;
    const float* u_p  = xconv_b + ((long)dir * 1024 + d0) * L;
    const float* B_p  = xdbl_b + ((long)dir * 64 + 32) * L;
    const float* C_p  = xdbl_b + ((long)dir * 64 + 48) * L;
    const float* z_p  = xz_b + ((dir ? 3072 : 1024) + (long)d0) * L;
    float* o_p = out_fb + ((dir ? 1024 : 0) + (long)d0) * L;
    const int lch = tid >> 4, lq = tid & 15;
    {
        float4 a = *(const float4*)(dl_p + (long)lch * L + t0 + lq * 4);
        float4 b = *(const float4*)(u_p + (long)lch * L + t0 + lq * 4);
        float4 w0; w0.x = a.x; w0.y = b.x; w0.z = a.y; w0.w = b.y;
        float4 w1; w1.x = a.z; w1.y = b.z; w1.z = a.w; w1.w = b.w;
        *(float4*)&s_dlu[lch][lq * 8] = w0;
        *(float4*)&s_dlu[lch][lq * 8 + 4] = w1;
        float4 c = *(const float4*)(B_p + (long)lch * L + t0 + lq * 4);
        float4 e = *(const float4*)(C_p + (long)lch * L + t0 + lq * 4);
        float4 x0; x0.x = c.x; x0.y = e.x; x0.z = c.y; x0.w = e.y;
        float4 x1; x1.x = c.z; x1.y = e.z; x1.z = c.w; x1.w = e.w;
        *(float4*)&s_BC[lch][lq * 8] = x0;
        *(float4*)&s_BC[lch][lq * 8 + 4] = x1;
    }
    __syncthreads();
    float h = hin[(((long)dir * NCH + ch) * 1024 + d) * 16 + n];
#pragma unroll 4
    for (int tt = 0; tt < STILE; ++tt) {
        float2 dlu = *(const float2*)&s_dlu[dloc][tt * 2];
        float2 bc = *(const float2*)&s_BC[n][tt * 2];
        float dA = __expf(dlu.x * Adn);
        h = fmaf(dA, h, dlu.x * dlu.y * bc.x);
        float y = row_reduce16(h * bc.y);
        if (n == 0) s_dlu[dloc][tt * 2] = y + Dd * dlu.y;
    }
    {
        float* po = o_p + (long)lch * L + opos0;
        const float* pz = z_p + (long)lch * L + opos0;
        int oo = lq * 4;
        float4 zv = *(const float4*)(pz + oo);
        float y0 = s_dlu[lch][(dir ? 63 - oo : oo) * 2];
        float y1 = s_dlu[lch][(dir ? 62 - oo : oo + 1) * 2];
        float y2 = s_dlu[lch][(dir ? 61 - oo : oo + 2) * 2];
        float y3 = s_dlu[lch][(dir ? 60 - oo : oo + 3) * 2];
        float4 r;
        r.x = y0 * (zv.x / (1.f + __expf(-zv.x)));
        r.y = y1 * (zv.y / (1.f + __expf(-zv.y)));
        r.z = y2 * (zv.z / (1.f + __expf(-zv.z)));
        r.w = y3 * (zv.w / (1.f + __expf(-zv.w)));
        *(float4*)(po + oo) = r;
    }
}

// ---------------------------------------------------------------------------
// Conv-branch helpers
// ---------------------------------------------------------------------------
__global__ __launch_bounds__(256) void mean_phi_kernel(
    const float* __restrict__ xz_b, const float* __restrict__ gw,
    const float* __restrict__ gb, float* __restrict__ phi_b)
{
    int c = blockIdx.x;
    const float* src = xz_b + (4608 + (long)c) * L;
    float s = 0.f;
    for (int l = threadIdx.x; l < L; l += 256) s += src[l];
    __shared__ float red[256];
    red[threadIdx.x] = s;
    __syncthreads();
    for (int st = 128; st > 0; st >>= 1) {
        if (threadIdx.x < st) red[threadIdx.x] += red[threadIdx.x + st];
        __syncthreads();
    }
    if (threadIdx.x == 0) {
        float m = red[0] / (float)L;
        phi_b[c] = fmaxf(gw[c] * m + gb[c], 0.f);
    }
}

// original flat cat_build (fallback path)
__global__ __launch_bounds__(256) void cat_build_kernel(
    const float* __restrict__ xz_b,
    const float* __restrict__ lw, const float* __restrict__ lb,
    const float* __restrict__ pw, const float* __restrict__ pb,
    const float* __restrict__ dw, const float* __restrict__ db,
    const float* __restrict__ phi_b, float* __restrict__ cat_b)
{
    long idx = (long)blockIdx.x * 256 + threadIdx.x;   // over 2048*L
    int l = (int)(idx % L);
    int cc = (int)(idx / L);
    float val;
    if (cc < 1536) {
        int i = cc >> 9, c = cc & 511, dil = 1 << i;  // dilations 1,2,4
        const float* xa = xz_b + (4096 + (long)c) * L;
        float pwv = pw[i * 512 + c], pbv = pb[i * 512 + c];
        const float* w = dw + ((long)i * 512 + c) * 3;
        float acc = db[i * 512 + c];
#pragma unroll
        for (int k = 0; k < 3; ++k) {
            int t = l + (k - 1) * dil;
            if (t >= 0 && t < L) acc += (pwv * xa[t] + pbv) * w[k];
        }
        val = acc;
    } else {
        int c = cc & 511;
        const float* xc = xz_b + (4608 + (long)c) * L;
        float acc = lb[c];
#pragma unroll
        for (int k = 0; k < 3; ++k) {
            int t = l - 1 + k;
            if (t >= 0 && t < L) acc += xc[t] * lw[c * 3 + k];
        }
        float g = 0.5f * acc * (1.f + erff(acc * 0.70710678118f));
        val = phi_b[c] * g;
    }
    cat_b[idx] = val;
}

// ---------------------------------------------------------------------------
// cat_build + transposed bf16 split + LN partial sums fused (MFMA path):
// 64x64 tiles; each block covers LN channel-group g=blockIdx.y exactly, so
// it writes lnps/lnpq[g][l] directly (no atomics). Channel mapping per
// thread is a contiguous 16-run (ty*16+q) accumulated in-register.
// ---------------------------------------------------------------------------
__global__ __launch_bounds__(256) void cat_build_bt_kernel(
    const float* __restrict__ xz_b,
    const float* __restrict__ lw, const float* __restrict__ lb,
    const float* __restrict__ pw, const float* __restrict__ pb,
    const float* __restrict__ dw, const float* __restrict__ db,
    const float* __restrict__ phi_b, float* __restrict__ cat_b,
    unsigned short* __restrict__ BT_hi, unsigned short* __restrict__ BT_lo,
    float* __restrict__ lnps, float* __restrict__ lnpq)
{
    __shared__ float tile[64][65];
    __shared__ float rs[4][64], rq[4][64];
    const int l0 = blockIdx.x * 64, c0 = blockIdx.y * 64;
    const int li = threadIdx.x & 63, ty = threadIdx.x >> 6;
    const int l = l0 + li;
    float s = 0.f, qs = 0.f;
#pragma unroll 4
    for (int q = 0; q < 16; ++q) {
        int ccl = ty * 16 + q;
        int cc = c0 + ccl;
        float val;
        if (cc < 1536) {
            int i = cc >> 9, c = cc & 511, dil = 1 << i;  // dilations 1,2,4
            const float* xa = xz_b + (4096 + (long)c) * L;
            float pwv = pw[i * 512 + c], pbv = pb[i * 512 + c];
            const float* w = dw + ((long)i * 512 + c) * 3;
            float acc = db[i * 512 + c];
#pragma unroll
            for (int k = 0; k < 3; ++k) {
                int t = l + (k - 1) * dil;
                if (t >= 0 && t < L) acc += (pwv * xa[t] + pbv) * w[k];
            }
            val = acc;
        } else {
            int c = cc & 511;
            const float* xc = xz_b + (4608 + (long)c) * L;
            float acc = lb[c];
#pragma unroll
            for (int k = 0; k < 3; ++k) {
                int t = l - 1 + k;
                if (t >= 0 && t < L) acc += xc[t] * lw[c * 3 + k];
            }
            float g = 0.5f * acc * (1.f + erff(acc * 0.70710678118f));
            val = phi_b[c] * g;
        }
        cat_b[(long)cc * L + l] = val;
        tile[ccl][li] = val;
        s += val;
        qs = fmaf(val, val, qs);
    }
    rs[ty][li] = s;
    rq[ty][li] = qs;
    __syncthreads();
    if (ty == 0) {
        float S = (rs[0][li] + rs[1][li]) + (rs[2][li] + rs[3][li]);
        float Q = (rq[0][li] + rq[1][li]) + (rq[2][li] + rq[3][li]);
        lnps[(long)blockIdx.y * L + l] = S;
        lnpq[(long)blockIdx.y * L + l] = Q;
    }
    const int ci = li;
#pragma unroll 4
    for (int q = 0; q < 16; ++q) {
        int ll = q * 4 + ty;
        float x = tile[ci][ll];
        unsigned short h, lo;
        split1(x, h, lo);
        long o = (long)(l0 + ll) * 2048 + c0 + ci;
        BT_hi[o] = h;
        BT_lo[o] = lo;
    }
}

// ---------------------------------------------------------------------------
// LN stats, two-stage coalesced.
// ---------------------------------------------------------------------------
__global__ __launch_bounds__(256) void ln_partial_kernel(
    const float* __restrict__ cat_b, float* __restrict__ ps, float* __restrict__ pq)
{
    int l = blockIdx.x * 256 + threadIdx.x;
    int g = blockIdx.y;                      // 32 groups x 64 channels
    const float* p = cat_b + (long)g * 64 * L + l;
    float s = 0.f, q = 0.f;
#pragma unroll 8
    for (int c = 0; c < 64; ++c) {
        float v = p[(long)c * L];
        s += v;
        q = fmaf(v, v, q);
    }
    ps[g * L + l] = s;
    pq[g * L + l] = q;
}

__global__ __launch_bounds__(256) void ln_final_kernel(
    const float* __restrict__ ps, const float* __restrict__ pq,
    float* __restrict__ mu_b, float* __restrict__ rsig_b)
{
    int l = blockIdx.x * 256 + threadIdx.x;
    float s = 0.f, q = 0.f;
#pragma unroll
    for (int g = 0; g < 32; ++g) {
        s += ps[g * L + l];
        q += pq[g * L + l];
    }
    float m = s * (1.f / 2048.f);
    float var = q * (1.f / 2048.f) - m * m;
    mu_b[l] = m;
    rsig_b[l] = rsqrtf(var + 1e-5f);
}

// old single-stage LN stats (fallback path only)
__global__ __launch_bounds__(256) void ln_stats_kernel(
    const float* __restrict__ cat_b, float* __restrict__ mu_b, float* __restrict__ rsig_b)
{
    int tx = threadIdx.x & 63, ty = threadIdx.x >> 6;
    int l = blockIdx.x * 64 + tx;
    float s = 0.f, s2 = 0.f;
    for (int c = ty; c < 2048; c += 4) {
        float v = cat_b[(long)c * L + l];
        s += v;
        s2 += v * v;
    }
    __shared__ float rs[4][64], rq[4][64];
    rs[ty][tx] = s;
    rq[ty][tx] = s2;
    __syncthreads();
    if (ty == 0) {
        float S = rs[0][tx] + rs[1][tx] + rs[2][tx] + rs[3][tx];
        float Q = rq[0][tx] + rq[1][tx] + rq[2][tx] + rq[3][tx];
        float m = S * (1.f / 2048.f);
        float var = Q * (1.f / 2048.f) - m * m;
        mu_b[l] = m;
        rsig_b[l] = rsqrtf(var + 1e-5f);
    }
}

// fuse_pre: f32 wg (fallback path)
__global__ __launch_bounds__(256) void fuse_pre_kernel(
    const float* __restrict__ fw, const float* __restrict__ g,
    const float* __restrict__ lbn, const float* __restrict__ fb,
    float* __restrict__ wg, float* __restrict__ S1, float* __restrict__ S2)
{
    int o = blockIdx.x;
    float s1 = 0.f, s2 = 0.f;
    for (int c = threadIdx.x; c < 2048; c += 256) {
        float w = fw[(long)o * 2048 + c];
        float v = w * g[c];
        wg[(long)o * 2048 + c] = v;
        s1 += v;
        s2 += w * lbn[c];
    }
    __shared__ float r1[256], r2[256];
    r1[threadIdx.x] = s1;
    r2[threadIdx.x] = s2;
    __syncthreads();
    for (int st = 128; st > 0; st >>= 1) {
        if (threadIdx.x < st) {
            r1[threadIdx.x] += r1[threadIdx.x + st];
            r2[threadIdx.x] += r2[threadIdx.x + st];
        }
        __syncthreads();
    }
    if (threadIdx.x == 0) {
        S1[o] = r1[0];
        S2[o] = r2[0] + fb[o];
    }
}

// fuse_pre with bf16 hi/lo split output (MFMA path)
__global__ __launch_bounds__(256) void fuse_pre_split_kernel(
    const float* __restrict__ fw, const float* __restrict__ g,
    const float* __restrict__ lbn, const float* __restrict__ fb,
    unsigned short* __restrict__ wg_hi, unsigned short* __restrict__ wg_lo,
    float* __restrict__ S1, float* __restrict__ S2)
{
    int o = blockIdx.x;
    float s1 = 0.f, s2 = 0.f;
    for (int c = threadIdx.x; c < 2048; c += 256) {
        float w = fw[(long)o * 2048 + c];
        float v = w * g[c];
        unsigned short h, l;
        split1(v, h, l);
        wg_hi[(long)o * 2048 + c] = h;
        wg_lo[(long)o * 2048 + c] = l;
        s1 += v;
        s2 += w * lbn[c];
    }
    __shared__ float r1[256], r2[256];
    r1[threadIdx.x] = s1;
    r2[threadIdx.x] = s2;
    __syncthreads();
    for (int st = 128; st > 0; st >>= 1) {
        if (threadIdx.x < st) {
            r1[threadIdx.x] += r1[threadIdx.x + st];
            r2[threadIdx.x] += r2[threadIdx.x + st];
        }
        __syncthreads();
    }
    if (threadIdx.x == 0) {
        S1[o] = r1[0];
        S2[o] = r2[0] + fb[o];
    }
}

extern "C" void kernel_launch(void* const* d_in, const int* in_sizes, int n_in,
                              void* d_out, int out_size, void* d_ws, size_t ws_size,
                              hipStream_t stream)
{
    const float* hidden     = (const float*)d_in[0];
    const float* in_proj_w  = (const float*)d_in[1];
    const float* conv1d_w   = (const float*)d_in[2];
    const float* conv1d_b   = (const float*)d_in[3];
    const float* x_proj_w   = (const float*)d_in[4];
    const float* dt_proj_w  = (const float*)d_in[5];
    const float* dt_proj_b  = (const float*)d_in[6];
    const float* A_log      = (const float*)d_in[7];
    const float* Dvec       = (const float*)d_in[8];
    const float* out_proj_w = (const float*)d_in[9];
    const float* cb_local_w = (const float*)d_in[10];
    const float* cb_local_b = (const float*)d_in[11];
    const float* cb_global_w= (const float*)d_in[12];
    const float* cb_global_b= (const float*)d_in[13];
    const float* cb_pre_w   = (const float*)d_in[14];
    const float* cb_pre_b   = (const float*)d_in[15];
    const float* cb_dil_w   = (const float*)d_in[16];
    const float* cb_dil_b   = (const float*)d_in[17];
    const float* cb_ln_g    = (const float*)d_in[18];
    const float* cb_ln_b    = (const float*)d_in[19];
    const float* cb_fuse_w  = (const float*)d_in[20];
    const float* cb_fuse_b  = (const float*)d_in[21];

    float* ws = (float*)d_ws;
    const size_t CSZ = (size_t)2 * NCH * 1024 * 16;            // 1179648 floats

    // ---------------- MFMA-tier layout (all counts in floats) ----------------
    size_t off = 0;
    float* S1    = ws + off; off += 1024;
    float* S2    = ws + off; off += 1024;
    float* xz_b  = ws + off; off += (size_t)5120 * L;
    float* out_fb= ws + off; off += (size_t)3072 * L;
    float* cat_b = ws + off; off += (size_t)2048 * L;
    float* delta_b = cat_b;   // delta written after LN stats consumed cat
    float* xconv_b = ws + off; off += (size_t)2048 * L;
    float* xdbl_b  = ws + off; off += (size_t)128 * L;
    float* mu_b    = ws + off; off += L;
    float* rsig_b  = ws + off; off += L;
    float* phi_b   = ws + off; off += 512;
    float* lnps    = ws + off; off += (size_t)32 * L;
    float* lnpq    = ws + off; off += (size_t)32 * L;
    float* hend = ws + off; off += CSZ;
    float* pAb  = ws + off; off += CSZ;
    float* hin  = ws + off; off += CSZ;
    unsigned short* wg_hi  = (unsigned short*)(ws + off); off += (size_t)1024 * 2048 / 2;
    unsigned short* wg_lo  = (unsigned short*)(ws + off); off += (size_t)1024 * 2048 / 2;
    unsigned short* inW_hi = (unsigned short*)(ws + off); off += (size_t)5120 * 512 / 2;
    unsigned short* inW_lo = (unsigned short*)(ws + off); off += (size_t)5120 * 512 / 2;
    unsigned short* outW_hi= (unsigned short*)(ws + off); off += (size_t)512 * 3072 / 2;
    unsigned short* outW_lo= (unsigned short*)(ws + off); off += (size_t)512 * 3072 / 2;
    unsigned short* BT_hi  = (unsigned short*)(ws + off); off += (size_t)3072 * L / 2;
    unsigned short* BT_lo  = (unsigned short*)(ws + off); off += (size_t)3072 * L / 2;
    size_t need_mfma = off * sizeof(float);                    // ~183 MB

    // x_proj split-K partials alias out_fb's scan region (dead at that point)
    float* xpP = out_fb;
    // fuse partials (4 x 1024 x L) and out_proj partials (8 x 512 x L) both
    // occupy 4096*L floats = the CONTIGUOUS cat_b+xconv_b region (both dead
    // at their respective points; same-stream ordering).
    float* fsP = cat_b;
    float* opP = cat_b;

    if (ws_size >= need_mfma) {
        // ================= MFMA split-bf16 path =================
        fuse_pre_split_kernel<<<1024, 256, 0, stream>>>(
            cb_fuse_w, cb_ln_g, cb_ln_b, cb_fuse_b, wg_hi, wg_lo, S1, S2);
        split_kernel<<<(5120 * 512) / 1024, 256, 0, stream>>>(in_proj_w, inW_hi, inW_lo, 5120 * 512);
        split_kernel<<<(512 * 3072) / 1024, 256, 0, stream>>>(out_proj_w, outW_hi, outW_lo, 512 * 3072);

        for (int b = 0; b < NB; ++b) {
            const float* hid_b = hidden + (size_t)b * L * 512;
            float* out_b = (float*)d_out + (size_t)b * L * 512;

            // hidden split -> BT region ([l][d] already k-contig)
            split_kernel<<<(L * 512) / 1024, 256, 0, stream>>>(hid_b, BT_hi, BT_lo, L * 512);
            // in_proj: xz_b[e][l]
            gemm_mfma<<<dim3(5120 / 128, L / 128), 256, 0, stream>>>(
                inW_hi, inW_lo, 512, BT_hi, BT_lo, 512,
                xz_b, L, 1, 512, 0, nullptr, nullptr, nullptr, nullptr);

            // conv branch: cat + transposed bf16 split + LN partials, one pass
            mean_phi_kernel<<<512, 256, 0, stream>>>(xz_b, cb_global_w, cb_global_b, phi_b);
            cat_build_bt_kernel<<<dim3(L / 64, 2048 / 64), 256, 0, stream>>>(
                xz_b, cb_local_w, cb_local_b, cb_pre_w, cb_pre_b, cb_dil_w, cb_dil_b,
                phi_b, cat_b, BT_hi, BT_lo, lnps, lnpq);
            ln_final_kernel<<<L / 256, 256, 0, stream>>>(lnps, lnpq, mu_b, rsig_b);
            // fuse GEMM: split-K (4 slices of 512), 128x128 tiles
            gemm_mfma128sk<<<dim3(1024 / 128, L / 128, 4), 256, 0, stream>>>(
                wg_hi, wg_lo, 2048, BT_hi, BT_lo, 2048, fsP, 512, 1024);
            // reduce + epilogue -> BT[l][3072] cols 2048.. (bf16 split, direct)
            fuse_reduce_bt<<<L, 256, 0, stream>>>(
                fsP, mu_b, rsig_b, S1, S2, BT_hi, BT_lo);

            // mamba branch
            mamba_conv_kernel<<<(2 * 1024 * L) / 256, 256, 0, stream>>>(
                xz_b, conv1d_w, conv1d_b, xconv_b);
            xproj_partial<<<dim3(L / 64, 2, 4), 256, 0, stream>>>(
                x_proj_w, xconv_b, xpP);
            xproj_reduce<<<(2 * 64 * L / 4) / 256, 256, 0, stream>>>(xpP, xdbl_b);
            gemm_f32<<<dim3(1024 / 64, L / 64, 2), 256, 0, stream>>>(
                dt_proj_w, 32, xdbl_b, L, 0, (long)64 * L,
                delta_b, L, 1, (long)1024 * L, 1024, L, 32,
                dt_proj_b, 1, nullptr, nullptr, nullptr, nullptr);
            scan_pass1<<<dim3(64, 2, NCH), 256, 0, stream>>>(
                delta_b, xconv_b, xdbl_b, A_log, hend, pAb);
            scan_fix<<<128, 256, 0, stream>>>(hend, pAb, hin);
            // scan output -> BT[l][3072] cols 0..2047 (bf16 split, direct)
            scan_pass2_bt<<<dim3(64, 2, NCH), 256, 0, stream>>>(
                delta_b, xconv_b, xdbl_b, xz_b, A_log, Dvec, hin, BT_hi, BT_lo);

            // out_proj: split-K (8 slices of 384), 128x128 tiles -> reduce
            gemm_mfma128sk<<<dim3(512 / 128, L / 128, 8), 256, 0, stream>>>(
                outW_hi, outW_lo, 3072, BT_hi, BT_lo, 3072, opP, 384, 512);
            out_reduce<<<(512 * L / 4) / 256, 256, 0, stream>>>(opP, out_b);
        }
        return;
    }

    // ================= fallback: f32 path (dedicated chunk buffers only) =====
    off = 0;
    float* wg    = ws + off; off += (size_t)1024 * 2048;
    S1    = ws + off; off += 1024;
    S2    = ws + off; off += 1024;
    xz_b  = ws + off; off += (size_t)5120 * L;
    out_fb= ws + off; off += (size_t)3072 * L;
    cat_b = ws + off; off += (size_t)2048 * L;
    delta_b = cat_b;
    xconv_b = ws + off; off += (size_t)2048 * L;
    xdbl_b  = ws + off; off += (size_t)128 * L;
    mu_b    = ws + off; off += L;
    rsig_b  = ws + off; off += L;
    phi_b   = ws + off; off += 512;
    hend = ws + off; off += CSZ;
    pAb  = ws + off; off += CSZ;
    hin  = ws + off; off += CSZ;
    if (ws_size < off * sizeof(float)) return;  // clean failure (diagnostic)

    fuse_pre_kernel<<<1024, 256, 0, stream>>>(cb_fuse_w, cb_ln_g, cb_ln_b, cb_fuse_b, wg, S1, S2);

    for (int b = 0; b < NB; ++b) {
        const float* hid_b = hidden + (size_t)b * L * 512;
        float* out_b = (float*)d_out + (size_t)b * L * 512;

        gemm_f32<<<dim3(5120 / 64, L / 64, 1), 256, 0, stream>>>(
            in_proj_w, 512, hid_b, 512, 1, 0,
            xz_b, L, 1, 0, 5120, L, 512,
            nullptr, 0, nullptr, nullptr, nullptr, nullptr);

        mean_phi_kernel<<<512, 256, 0, stream>>>(xz_b, cb_global_w, cb_global_b, phi_b);
        cat_build_kernel<<<(2048 * L) / 256, 256, 0, stream>>>(
            xz_b, cb_local_w, cb_local_b, cb_pre_w, cb_pre_b, cb_dil_w, cb_dil_b, phi_b, cat_b);
        ln_stats_kernel<<<L / 64, 256, 0, stream>>>(cat_b, mu_b, rsig_b);
        gemm_f32<<<dim3(1024 / 64, L / 64, 1), 256, 0, stream>>>(
            wg, 2048, cat_b, L, 0, 0,
            out_fb + (long)2048 * L, L, 1, 0, 1024, L, 2048,
            nullptr, 2, mu_b, rsig_b, S1, S2);

        mamba_conv_kernel<<<(2 * 1024 * L) / 256, 256, 0, stream>>>(
            xz_b, conv1d_w, conv1d_b, xconv_b);
        gemm_f32<<<dim3(1, L / 64, 2), 256, 0, stream>>>(
            x_proj_w, 1024, xconv_b, L, 0, (long)1024 * L,
            xdbl_b, L, 1, (long)64 * L, 64, L, 1024,
            nullptr, 0, nullptr, nullptr, nullptr, nullptr);
        gemm_f32<<<dim3(1024 / 64, L / 64, 2), 256, 0, stream>>>(
            dt_proj_w, 32, xdbl_b, L, 0, (long)64 * L,
            delta_b, L, 1, (long)1024 * L, 1024, L, 32,
            dt_proj_b, 1, nullptr, nullptr, nullptr, nullptr);
        scan_pass1<<<dim3(64, 2, NCH), 256, 0, stream>>>(
            delta_b, xconv_b, xdbl_b, A_log, hend, pAb);
        scan_fix<<<128, 256, 0, stream>>>(hend, pAb, hin);
        scan_pass2<<<dim3(64, 2, NCH), 256, 0, stream>>>(
            delta_b, xconv_b, xdbl_b, xz_b, A_log, Dvec, hin, out_fb);

        gemm_f32<<<dim3(512 / 64, L / 64, 1), 256, 0, stream>>>(
            out_proj_w, 3072, out_fb, L, 0, 0,
            out_b, 1, 512, 0, 512, L, 3072,
            nullptr, 0, nullptr, nullptr, nullptr, nullptr);
    }
}